// Round 4
// baseline (33710.928 us; speedup 1.0000x reference)
//
#include <hip/hip_runtime.h>
#include <math.h>

// ---------------------------------------------------------------------------
// LSTM_DNC round 4: flag-broadcast barriers + machinery/GEMM overlap.
//  - dnc: blocks 0..63 = machinery only (batch=bk); blocks 64..255 = GEMM,
//    4 cells each (1024 thr, 16 waves = 4 cells x 4 K-quarters).
//  - Pipeline: [acc128(rv) + finish gates + h-store] -> full flag barrier ->
//    [acc768(t+1)  ||  machinery(t) -> rv + 64 flags] -> flags2 wait -> loop.
//  - Barriers: per-block release flag store + one wave polls coalesced; no
//    atomic RMW chains. Fences: per-wave release before flag, acquire after.
// ---------------------------------------------------------------------------

#define EPSF 1e-6f

__device__ __forceinline__ float sigmoidf_(float x) { return 1.f / (1.f + expf(-x)); }
__device__ __forceinline__ float softplusf_(float x) {
    return (x > 0.f) ? x + log1pf(expf(-x)) : log1pf(expf(x));
}
__device__ __forceinline__ void st_flag(int* p, int v) {
    __hip_atomic_store(p, v, __ATOMIC_RELAXED, __HIP_MEMORY_SCOPE_AGENT);
}
__device__ __forceinline__ int ld_flag(const int* p) {
    return __hip_atomic_load(p, __ATOMIC_RELAXED, __HIP_MEMORY_SCOPE_AGENT);
}
// poll flags[64..255] >= tgt (one wave)
__device__ __forceinline__ void poll_g(const int* f, int lane, int tgt) {
    for (;;) {
        int a = ld_flag(f + 64 + lane);
        int b = ld_flag(f + 128 + lane);
        int c = ld_flag(f + 192 + lane);
        int m = min(min(a, b), c);
        if (__all(m >= tgt)) break;
        __builtin_amdgcn_s_sleep(1);
    }
}
// poll flags[0..63] >= tgt (one wave)
__device__ __forceinline__ void poll_m(const int* f, int lane, int tgt) {
    for (;;) {
        if (__all(ld_flag(f + lane) >= tgt)) break;
        __builtin_amdgcn_s_sleep(1);
    }
}
// poll flags[0..255] >= tgt (one wave)
__device__ __forceinline__ void poll_all(const int* f, int lane, int tgt) {
    for (;;) {
        int a = ld_flag(f + lane);
        int b = ld_flag(f + 64 + lane);
        int c = ld_flag(f + 128 + lane);
        int d = ld_flag(f + 192 + lane);
        int m = min(min(a, b), min(c, d));
        if (__all(m >= tgt)) break;
        __builtin_amdgcn_s_sleep(1);
    }
}

// ---------------------------------------------------------------------------
// prep: Wcat[3036][896]: cols 0..758 = Whh_c, 759..767 = 0, 768..895 = Wih_c rv part
// ---------------------------------------------------------------------------
__global__ __launch_bounds__(256) void prep_weights(const float* __restrict__ Whh_c,
                                                    const float* __restrict__ Wih_c,
                                                    float* __restrict__ Wcat) {
    int idx = blockIdx.x * 256 + threadIdx.x;
    if (idx < 3036 * 896) {
        int r = idx / 896, j = idx - r * 896;
        float v;
        if (j < 759) v = Whh_c[r * 759 + j];
        else if (j < 768) v = 0.f;
        else v = Wih_c[r * 640 + 512 + (j - 768)];
        Wcat[idx] = v;
    }
}

// ---------------------------------------------------------------------------
// proj_gemm: OUT^T[j][m] = bias[j] + sum_{k<512} A[arow(m)][k] * W[j][k]
// ---------------------------------------------------------------------------
__global__ __launch_bounds__(256, 2) void proj_gemm(const float* __restrict__ A,
                                                    const float* __restrict__ W,
                                                    const float* __restrict__ bias,
                                                    float* __restrict__ OUT, int Ncols,
                                                    int wstride, int arow_base, int arow_stride_t,
                                                    int arow_stride_b, int arowlen, int Mrows) {
    __shared__ float As[16 * 68];
    __shared__ float Ws[16 * 68];
    const int tid = threadIdx.x;
    const int ntile = blockIdx.x, mtile = blockIdx.y;
    const int tx = tid & 15, ty = tid >> 4;
    const int lr = tid >> 2;
    const int lk = (tid & 3) * 4;
    const size_t arow =
        (size_t)arow_base + (size_t)mtile * arow_stride_t + (size_t)lr * arow_stride_b;
    const float* aptr = A + arow * arowlen + lk;
    const int wn = ntile * 64 + lr;
    const bool wok = (wn < Ncols);
    const float* wptr = W + (size_t)(wok ? wn : 0) * wstride + lk;
    float acc[4][4] = {};
    for (int kt = 0; kt < 512; kt += 16) {
        float4 av = *(const float4*)(aptr + kt);
        float4 w4l = *(const float4*)(wptr + kt);
        if (!wok) w4l = make_float4(0.f, 0.f, 0.f, 0.f);
        __syncthreads();
        As[(lk + 0) * 68 + lr] = av.x;
        As[(lk + 1) * 68 + lr] = av.y;
        As[(lk + 2) * 68 + lr] = av.z;
        As[(lk + 3) * 68 + lr] = av.w;
        Ws[(lk + 0) * 68 + lr] = w4l.x;
        Ws[(lk + 1) * 68 + lr] = w4l.y;
        Ws[(lk + 2) * 68 + lr] = w4l.z;
        Ws[(lk + 3) * 68 + lr] = w4l.w;
        __syncthreads();
#pragma unroll
        for (int k = 0; k < 16; ++k) {
            float4 a4 = *(const float4*)&As[k * 68 + ty * 4];
            float4 w4 = *(const float4*)&Ws[k * 68 + tx * 4];
            acc[0][0] = fmaf(a4.x, w4.x, acc[0][0]);
            acc[0][1] = fmaf(a4.x, w4.y, acc[0][1]);
            acc[0][2] = fmaf(a4.x, w4.z, acc[0][2]);
            acc[0][3] = fmaf(a4.x, w4.w, acc[0][3]);
            acc[1][0] = fmaf(a4.y, w4.x, acc[1][0]);
            acc[1][1] = fmaf(a4.y, w4.y, acc[1][1]);
            acc[1][2] = fmaf(a4.y, w4.z, acc[1][2]);
            acc[1][3] = fmaf(a4.y, w4.w, acc[1][3]);
            acc[2][0] = fmaf(a4.z, w4.x, acc[2][0]);
            acc[2][1] = fmaf(a4.z, w4.y, acc[2][1]);
            acc[2][2] = fmaf(a4.z, w4.z, acc[2][2]);
            acc[2][3] = fmaf(a4.z, w4.w, acc[2][3]);
            acc[3][0] = fmaf(a4.w, w4.x, acc[3][0]);
            acc[3][1] = fmaf(a4.w, w4.y, acc[3][1]);
            acc[3][2] = fmaf(a4.w, w4.z, acc[3][2]);
            acc[3][3] = fmaf(a4.w, w4.w, acc[3][3]);
        }
    }
    const int col0 = ntile * 64 + tx * 4;
    const int row0 = mtile * 64 + ty * 4;
#pragma unroll
    for (int j = 0; j < 4; ++j) {
        int col = col0 + j;
        if (col < Ncols) {
            float bv = bias[col];
            float4 st = make_float4(acc[0][j] + bv, acc[1][j] + bv, acc[2][j] + bv,
                                    acc[3][j] + bv);
            *(float4*)&OUT[(size_t)col * Mrows + row0] = st;
        }
    }
}

// ---------------------------------------------------------------------------
// enc_seq: 256 blocks x 512 threads; cell = bk + 256*cidx (2 cells), K-quarter q.
// Flag barrier per step.
// ---------------------------------------------------------------------------
__global__ __launch_bounds__(512, 1) void enc_seq(const float* __restrict__ Whh,
                                                  const float* __restrict__ XPT,
                                                  float* __restrict__ HXE,
                                                  float* __restrict__ CE,
                                                  float* __restrict__ ENC, int M, int t0, int TC,
                                                  int* flags) {
    __shared__ float part[8 * 4 * 64];
    const int tid = threadIdx.x;
    const int bk = blockIdx.x;
    const int lane = tid & 63;
    const int wv = __builtin_amdgcn_readfirstlane(tid >> 6);
    const int q = wv & 3, cidx = wv >> 2;
    const int cell = bk + 256 * cidx;
    const float* __restrict__ w0 = Whh + ((size_t)(0 * 512 + cell)) * 512 + q * 128;
    const float* __restrict__ w1 = Whh + ((size_t)(1 * 512 + cell)) * 512 + q * 128;
    const float* __restrict__ w2 = Whh + ((size_t)(2 * 512 + cell)) * 512 + q * 128;
    const float* __restrict__ w3 = Whh + ((size_t)(3 * 512 + cell)) * 512 + q * 128;
    float c_reg = 0.f;
    if (q == 0) c_reg = CE[cell * 64 + lane];
    for (int tl = 0; tl < TC; ++tl) {
        const int t = t0 + tl;
        const int rb = t & 1, wb = rb ^ 1;
        float x0 = 0.f, x1 = 0.f, x2 = 0.f, x3 = 0.f;
        if (q == 0) {
            const int m = tl * 64 + lane;
            x0 = XPT[(size_t)(0 * 512 + cell) * M + m];
            x1 = XPT[(size_t)(1 * 512 + cell) * M + m];
            x2 = XPT[(size_t)(2 * 512 + cell) * M + m];
            x3 = XPT[(size_t)(3 * 512 + cell) * M + m];
        }
        float a0 = 0.f, a1 = 0.f, a2 = 0.f, a3 = 0.f;
        {
            const float4* __restrict__ hx = (const float4*)HXE + (size_t)rb * 8192 + q * 32 * 64;
#pragma unroll 8
            for (int i = 0; i < 32; ++i) {
                float4 hv = hx[i * 64 + lane];
                float4 q0 = *(const float4*)&w0[i * 4];
                float4 q1 = *(const float4*)&w1[i * 4];
                float4 q2 = *(const float4*)&w2[i * 4];
                float4 q3 = *(const float4*)&w3[i * 4];
                a0 = fmaf(hv.x, q0.x, a0); a0 = fmaf(hv.y, q0.y, a0);
                a0 = fmaf(hv.z, q0.z, a0); a0 = fmaf(hv.w, q0.w, a0);
                a1 = fmaf(hv.x, q1.x, a1); a1 = fmaf(hv.y, q1.y, a1);
                a1 = fmaf(hv.z, q1.z, a1); a1 = fmaf(hv.w, q1.w, a1);
                a2 = fmaf(hv.x, q2.x, a2); a2 = fmaf(hv.y, q2.y, a2);
                a2 = fmaf(hv.z, q2.z, a2); a2 = fmaf(hv.w, q2.w, a2);
                a3 = fmaf(hv.x, q3.x, a3); a3 = fmaf(hv.y, q3.y, a3);
                a3 = fmaf(hv.z, q3.z, a3); a3 = fmaf(hv.w, q3.w, a3);
            }
        }
        part[(wv * 4 + 0) * 64 + lane] = a0;
        part[(wv * 4 + 1) * 64 + lane] = a1;
        part[(wv * 4 + 2) * 64 + lane] = a2;
        part[(wv * 4 + 3) * 64 + lane] = a3;
        __syncthreads();
        if (q == 0) {
            float g4[4];
#pragma unroll
            for (int g = 0; g < 4; ++g) {
                g4[g] = part[((cidx * 4 + 0) * 4 + g) * 64 + lane] +
                        part[((cidx * 4 + 1) * 4 + g) * 64 + lane] +
                        part[((cidx * 4 + 2) * 4 + g) * 64 + lane] +
                        part[((cidx * 4 + 3) * 4 + g) * 64 + lane];
            }
            float cc = sigmoidf_(g4[1] + x1) * c_reg + sigmoidf_(g4[0] + x0) * tanhf(g4[2] + x2);
            float hh = sigmoidf_(g4[3] + x3) * tanhf(cc);
            c_reg = cc;
            HXE[(size_t)wb * 32768 + (cell >> 2) * 256 + lane * 4 + (cell & 3)] = hh;
            ENC[((size_t)t * 64 + lane) * 512 + cell] = hh;
            __builtin_amdgcn_fence(__ATOMIC_RELEASE, "agent");
        }
        __syncthreads();
        if (tid == 0) st_flag(flags + bk, tl + 1);
        if (tl + 1 < TC) {
            if (wv == 0) poll_all(flags, lane, tl + 1);
            __syncthreads();
            __builtin_amdgcn_fence(__ATOMIC_ACQUIRE, "agent");
        }
    }
    if (q == 0) CE[cell * 64 + lane] = c_reg;
}

// ---------------------------------------------------------------------------
// dnc_seq: 256 blocks x 1024 threads.
//  blocks 64..255: GEMM, cell = (bk-64) + 192*cidx (cidx=wv>>2, q=wv&3).
//  blocks 0..63:  machinery for batch bk.
//  HXf buffers: 224 rows x 64 lanes x float4; rows 0..191 = h (k<768),
//  rows 192..223 = rv (k in 768..895).
// ---------------------------------------------------------------------------
__global__ __launch_bounds__(1024, 1) void dnc_seq(
    const float* __restrict__ Wcat, const float* __restrict__ CPT, float* __restrict__ HXf,
    float* __restrict__ CC, float* __restrict__ Mg, float* __restrict__ Ug,
    float* __restrict__ Pg, float* __restrict__ WWg, float* __restrict__ Lg,
    float* __restrict__ WRg, float* __restrict__ OUT, int M, int t0, int TC, int* flags) {
    __shared__ float part[16 * 4 * 64];
    __shared__ float M_l[64 * 33];
    __shared__ float L_l[64 * 65];
    __shared__ float act[256];
    __shared__ float wr_l[256];
    __shared__ float u_l[64], p_l[64], ww_l[64], cw_l[64], sM2[64], srt_l[64], asrt_l[64];
    __shared__ int rank_l[64];
    __shared__ float modes_l[12], kss_l[4], scal[4];

    const int tid = threadIdx.x;
    const int bk = blockIdx.x;
    const int lane = tid & 63;
    const int wv = __builtin_amdgcn_readfirstlane(tid >> 6);
    const int q = wv & 3, cidx = wv >> 2;
    const bool machb = (bk < 64);
    const int cell = machb ? 0 : (bk - 64) + 192 * cidx;
    const bool valid = !machb && (cell < 759);
    const int b = bk;
    int* flags2 = flags + 256;

    const float* __restrict__ wh0 = Wcat + (size_t)(0 * 759 + cell) * 896 + q * 192;
    const float* __restrict__ wh1 = Wcat + (size_t)(1 * 759 + cell) * 896 + q * 192;
    const float* __restrict__ wh2 = Wcat + (size_t)(2 * 759 + cell) * 896 + q * 192;
    const float* __restrict__ wh3 = Wcat + (size_t)(3 * 759 + cell) * 896 + q * 192;
    const float* __restrict__ wr0 = Wcat + (size_t)(0 * 759 + cell) * 896 + 768 + q * 32;
    const float* __restrict__ wr1 = Wcat + (size_t)(1 * 759 + cell) * 896 + 768 + q * 32;
    const float* __restrict__ wr2 = Wcat + (size_t)(2 * 759 + cell) * 896 + 768 + q * 32;
    const float* __restrict__ wr3 = Wcat + (size_t)(3 * 759 + cell) * 896 + 768 + q * 32;

    float c_reg = 0.f;
    if (valid && q == 0) c_reg = CC[cell * 64 + lane];

    if (machb) {
        if (tid < 256) {
#pragma unroll
            for (int i = 0; i < 8; ++i) {
                int e = tid + 256 * i;
                M_l[(e >> 5) * 33 + (e & 31)] = Mg[b * 2048 + e];
            }
#pragma unroll
            for (int i = 0; i < 16; ++i) {
                int e = tid + 256 * i;
                L_l[(e >> 6) * 65 + (e & 63)] = Lg[b * 4096 + e];
            }
            wr_l[tid] = WRg[b * 256 + tid];
        }
        if (tid < 64) {
            u_l[tid] = Ug[b * 64 + tid];
            p_l[tid] = Pg[b * 64 + tid];
            ww_l[tid] = WWg[b * 64 + tid];
        }
        __syncthreads();
    }

    float A0 = 0.f, A1 = 0.f, A2 = 0.f, A3 = 0.f;
    // prologue: acc768 for step t0 from buffer t0&1
    if (valid) {
        const float4* __restrict__ hx =
            (const float4*)HXf + (size_t)(t0 & 1) * 14336 + q * 48 * 64;
#pragma unroll 8
        for (int i = 0; i < 48; ++i) {
            float4 hv = hx[i * 64 + lane];
            float4 u0 = *(const float4*)&wh0[i * 4];
            float4 u1 = *(const float4*)&wh1[i * 4];
            float4 u2 = *(const float4*)&wh2[i * 4];
            float4 u3 = *(const float4*)&wh3[i * 4];
            A0 = fmaf(hv.x, u0.x, A0); A0 = fmaf(hv.y, u0.y, A0);
            A0 = fmaf(hv.z, u0.z, A0); A0 = fmaf(hv.w, u0.w, A0);
            A1 = fmaf(hv.x, u1.x, A1); A1 = fmaf(hv.y, u1.y, A1);
            A1 = fmaf(hv.z, u1.z, A1); A1 = fmaf(hv.w, u1.w, A1);
            A2 = fmaf(hv.x, u2.x, A2); A2 = fmaf(hv.y, u2.y, A2);
            A2 = fmaf(hv.z, u2.z, A2); A2 = fmaf(hv.w, u2.w, A2);
            A3 = fmaf(hv.x, u3.x, A3); A3 = fmaf(hv.y, u3.y, A3);
            A3 = fmaf(hv.z, u3.z, A3); A3 = fmaf(hv.w, u3.w, A3);
        }
    }

    for (int tl = 0; tl < TC; ++tl) {
        const int t = t0 + tl;
        const int rb = t & 1, wb = rb ^ 1;
        const bool last = (tl + 1 == TC);
        if (!machb) {
            // ---- finish gates: rv part (K=128) ----
            float b0 = 0.f, b1 = 0.f, b2 = 0.f, b3 = 0.f;
            float p0 = 0.f, p1 = 0.f, p2 = 0.f, p3 = 0.f;
            if (valid && q == 0) {
                const int m = tl * 64 + lane;
                p0 = CPT[(size_t)(0 * 759 + cell) * M + m];
                p1 = CPT[(size_t)(1 * 759 + cell) * M + m];
                p2 = CPT[(size_t)(2 * 759 + cell) * M + m];
                p3 = CPT[(size_t)(3 * 759 + cell) * M + m];
            }
            if (valid) {
                const float4* __restrict__ hx =
                    (const float4*)HXf + (size_t)rb * 14336 + (192 + q * 8) * 64;
#pragma unroll
                for (int i = 0; i < 8; ++i) {
                    float4 hv = hx[i * 64 + lane];
                    float4 u0 = *(const float4*)&wr0[i * 4];
                    float4 u1 = *(const float4*)&wr1[i * 4];
                    float4 u2 = *(const float4*)&wr2[i * 4];
                    float4 u3 = *(const float4*)&wr3[i * 4];
                    b0 = fmaf(hv.x, u0.x, b0); b0 = fmaf(hv.y, u0.y, b0);
                    b0 = fmaf(hv.z, u0.z, b0); b0 = fmaf(hv.w, u0.w, b0);
                    b1 = fmaf(hv.x, u1.x, b1); b1 = fmaf(hv.y, u1.y, b1);
                    b1 = fmaf(hv.z, u1.z, b1); b1 = fmaf(hv.w, u1.w, b1);
                    b2 = fmaf(hv.x, u2.x, b2); b2 = fmaf(hv.y, u2.y, b2);
                    b2 = fmaf(hv.z, u2.z, b2); b2 = fmaf(hv.w, u2.w, b2);
                    b3 = fmaf(hv.x, u3.x, b3); b3 = fmaf(hv.y, u3.y, b3);
                    b3 = fmaf(hv.z, u3.z, b3); b3 = fmaf(hv.w, u3.w, b3);
                }
            }
            part[(wv * 4 + 0) * 64 + lane] = A0 + b0;
            part[(wv * 4 + 1) * 64 + lane] = A1 + b1;
            part[(wv * 4 + 2) * 64 + lane] = A2 + b2;
            part[(wv * 4 + 3) * 64 + lane] = A3 + b3;
            __syncthreads();
            if (valid && q == 0) {
                float g4[4];
#pragma unroll
                for (int g = 0; g < 4; ++g) {
                    g4[g] = part[((cidx * 4 + 0) * 4 + g) * 64 + lane] +
                            part[((cidx * 4 + 1) * 4 + g) * 64 + lane] +
                            part[((cidx * 4 + 2) * 4 + g) * 64 + lane] +
                            part[((cidx * 4 + 3) * 4 + g) * 64 + lane];
                }
                float cc =
                    sigmoidf_(g4[1] + p1) * c_reg + sigmoidf_(g4[0] + p0) * tanhf(g4[2] + p2);
                float hh = sigmoidf_(g4[3] + p3) * tanhf(cc);
                c_reg = cc;
                HXf[(size_t)wb * 57344 + (cell >> 2) * 256 + lane * 4 + (cell & 3)] = hh;
                if (cell < 512) OUT[(size_t)lane * 131072 + (size_t)t * 512 + cell] = hh;
                __builtin_amdgcn_fence(__ATOMIC_RELEASE, "agent");
            }
            __syncthreads();
            if (tid == 0) st_flag(flags + bk, tl + 1);
            if (!last) {
                if (wv == 0) poll_g(flags, lane, tl + 1);
                __syncthreads();
                __builtin_amdgcn_fence(__ATOMIC_ACQUIRE, "agent");
                // ---- overlap: acc768 for step t+1 from buffer wb ----
                A0 = A1 = A2 = A3 = 0.f;
                if (valid) {
                    const float4* __restrict__ hx =
                        (const float4*)HXf + (size_t)wb * 14336 + q * 48 * 64;
#pragma unroll 8
                    for (int i = 0; i < 48; ++i) {
                        float4 hv = hx[i * 64 + lane];
                        float4 u0 = *(const float4*)&wh0[i * 4];
                        float4 u1 = *(const float4*)&wh1[i * 4];
                        float4 u2 = *(const float4*)&wh2[i * 4];
                        float4 u3 = *(const float4*)&wh3[i * 4];
                        A0 = fmaf(hv.x, u0.x, A0); A0 = fmaf(hv.y, u0.y, A0);
                        A0 = fmaf(hv.z, u0.z, A0); A0 = fmaf(hv.w, u0.w, A0);
                        A1 = fmaf(hv.x, u1.x, A1); A1 = fmaf(hv.y, u1.y, A1);
                        A1 = fmaf(hv.z, u1.z, A1); A1 = fmaf(hv.w, u1.w, A1);
                        A2 = fmaf(hv.x, u2.x, A2); A2 = fmaf(hv.y, u2.y, A2);
                        A2 = fmaf(hv.z, u2.z, A2); A2 = fmaf(hv.w, u2.w, A2);
                        A3 = fmaf(hv.x, u3.x, A3); A3 = fmaf(hv.y, u3.y, A3);
                        A3 = fmaf(hv.z, u3.z, A3); A3 = fmaf(hv.w, u3.w, A3);
                    }
                }
                if (wv == 0) poll_m(flags2, lane, tl + 1);
                __syncthreads();
                __builtin_amdgcn_fence(__ATOMIC_ACQUIRE, "agent");
            }
        } else {
            // ---------------- machinery block (batch = bk) ----------------
            if (wv == 0) poll_g(flags, lane, tl + 1);
            __syncthreads();
            __builtin_amdgcn_fence(__ATOMIC_ACQUIRE, "agent");
            const float* __restrict__ HXw = HXf + (size_t)wb * 57344;
            if (tid < 247) {
                float v = HXw[(128 + (tid >> 2)) * 256 + b * 4 + (tid & 3)];
                float a;
                if (tid < 128) a = tanhf(v);
                else if (tid < 132) a = softplusf_(v);
                else if (tid < 164) a = tanhf(v);
                else if (tid == 164) a = softplusf_(v);
                else if (tid < 197) a = sigmoidf_(v);
                else if (tid < 229) a = tanhf(v);
                else if (tid < 235) a = sigmoidf_(v);
                else a = v;
                act[tid] = a;
            }
            __syncthreads();
            if (tid < 4) {
                float m0 = act[235 + 3 * tid], m1 = act[236 + 3 * tid], m2 = act[237 + 3 * tid];
                float mx = fmaxf(m0, fmaxf(m1, m2));
                float e0 = expf(m0 - mx), e1 = expf(m1 - mx), e2 = expf(m2 - mx);
                float s = e0 + e1 + e2;
                modes_l[3 * tid] = e0 / s;
                modes_l[3 * tid + 1] = e1 / s;
                modes_l[3 * tid + 2] = e2 / s;
                float ks = 0.f;
                for (int w = 0; w < 32; ++w) {
                    float kk = act[tid * 32 + w];
                    ks = fmaf(kk, kk, ks);
                }
                kss_l[tid] = ks;
            }
            if (tid == 64) {
                float s = 0.f;
                for (int w = 0; w < 32; ++w) {
                    float kk = act[132 + w];
                    s = fmaf(kk, kk, s);
                }
                scal[0] = s;
            }
            if (tid < 64) {
                float psi = 1.f;
#pragma unroll
                for (int r = 0; r < 4; ++r) psi *= 1.f - act[229 + r] * wr_l[r * 64 + tid];
                float un = u_l[tid], wwn = ww_l[tid];
                u_l[tid] = (un + wwn - un * wwn) * psi;
                float s2 = 0.f;
                for (int w = 0; w < 32; ++w) {
                    float mm = M_l[tid * 33 + w];
                    s2 = fmaf(mm, mm, s2);
                }
                sM2[tid] = s2;
            }
            __syncthreads();
            if (tid < 64) {
                float un = u_l[tid];
                int rk = 0;
                for (int m = 0; m < 64; ++m) {
                    float um = u_l[m];
                    rk += (um < un) || (um == un && m < tid);
                }
                srt_l[rk] = un;
                rank_l[tid] = rk;
            }
            __syncthreads();
            if (tid < 64) {
                float v = srt_l[tid];
                float incl = v;
#pragma unroll
                for (int off = 1; off < 64; off <<= 1) {
                    float o = __shfl_up(incl, off);
                    if (tid >= off) incl *= o;
                }
                float excl = __shfl_up(incl, 1);
                if (tid == 0) excl = 1.f;
                asrt_l[tid] = (1.f - v) * excl;
                float dot = 0.f;
                for (int w = 0; w < 32; ++w) dot = fmaf(act[132 + w], M_l[tid * 33 + w], dot);
                float logit = dot * rsqrtf(sM2[tid] + EPSF) * rsqrtf(scal[0] + EPSF) * act[164];
                float mx = logit;
#pragma unroll
                for (int off = 32; off; off >>= 1) mx = fmaxf(mx, __shfl_xor(mx, off));
                float e = expf(logit - mx);
                float s = e;
#pragma unroll
                for (int off = 32; off; off >>= 1) s += __shfl_xor(s, off);
                cw_l[tid] = e / s;
            }
            __syncthreads();
            if (tid < 64) {
                float a = asrt_l[rank_l[tid]];
                float agv = act[233], wgv = act[234];
                float wn = wgv * (agv * a + (1.f - agv) * cw_l[tid]);
                ww_l[tid] = wn;
                float s = wn;
#pragma unroll
                for (int off = 32; off; off >>= 1) s += __shfl_xor(s, off);
                if (tid == 0) scal[1] = s;
            }
            __syncthreads();
            if (tid < 256) {
#pragma unroll
                for (int i = 0; i < 8; ++i) {
                    int e = tid + 256 * i;
                    int n = e >> 5, w = e & 31;
                    float wwn = ww_l[n];
                    M_l[n * 33 + w] =
                        M_l[n * 33 + w] * (1.f - wwn * act[165 + w]) + wwn * act[197 + w];
                }
#pragma unroll
                for (int i = 0; i < 16; ++i) {
                    int e = tid + 256 * i;
                    int n = e >> 6, m = e & 63;
                    float Lv = L_l[n * 65 + m];
                    Lv = (1.f - ww_l[n] - ww_l[m]) * Lv + ww_l[n] * p_l[m];
                    L_l[n * 65 + m] = (n == m) ? 0.f : Lv;
                }
            }
            __syncthreads();
            if (tid < 64) {
                p_l[tid] = (1.f - scal[1]) * p_l[tid] + ww_l[tid];
                float s2 = 0.f;
                for (int w = 0; w < 32; ++w) {
                    float mm = M_l[tid * 33 + w];
                    s2 = fmaf(mm, mm, s2);
                }
                sM2[tid] = s2;
            }
            __syncthreads();
            float wrn = 0.f;
            if (tid < 256) {
                const int r = wv;
                const int n = lane;
                float dot = 0.f;
                for (int w = 0; w < 32; ++w) dot = fmaf(act[r * 32 + w], M_l[n * 33 + w], dot);
                float logit = dot * rsqrtf(sM2[n] + EPSF) * rsqrtf(kss_l[r] + EPSF) * act[128 + r];
                float mx = logit;
#pragma unroll
                for (int off = 32; off; off >>= 1) mx = fmaxf(mx, __shfl_xor(mx, off));
                float e = expf(logit - mx);
                float s = e;
#pragma unroll
                for (int off = 32; off; off >>= 1) s += __shfl_xor(s, off);
                float cr = e / s;
                float fw = 0.f, bw = 0.f;
                for (int m = 0; m < 64; ++m) {
                    float wrm = wr_l[r * 64 + m];
                    fw = fmaf(L_l[n * 65 + m], wrm, fw);
                    bw = fmaf(L_l[m * 65 + n], wrm, bw);
                }
                wrn = modes_l[r * 3] * bw + modes_l[r * 3 + 1] * cr + modes_l[r * 3 + 2] * fw;
            }
            __syncthreads();
            if (tid < 256) wr_l[tid] = wrn;
            __syncthreads();
            if (tid < 128) {
                const int r = tid >> 5, w = tid & 31;
                float rv = 0.f;
                for (int n = 0; n < 64; ++n) rv = fmaf(wr_l[r * 64 + n], M_l[n * 33 + w], rv);
                HXf[(size_t)wb * 57344 + (192 + (tid >> 2)) * 256 + b * 4 + (tid & 3)] = rv;
            }
            if (wv < 2) __builtin_amdgcn_fence(__ATOMIC_RELEASE, "agent");
            __syncthreads();
            if (tid == 0) st_flag(flags2 + bk, tl + 1);
        }
    }
    if (valid && q == 0) CC[cell * 64 + lane] = c_reg;
    if (machb) {
        if (tid < 256) {
#pragma unroll
            for (int i = 0; i < 8; ++i) {
                int e = tid + 256 * i;
                Mg[b * 2048 + e] = M_l[(e >> 5) * 33 + (e & 31)];
            }
#pragma unroll
            for (int i = 0; i < 16; ++i) {
                int e = tid + 256 * i;
                Lg[b * 4096 + e] = L_l[(e >> 6) * 65 + (e & 63)];
            }
            WRg[b * 256 + tid] = wr_l[tid];
        }
        if (tid < 64) {
            Ug[b * 64 + tid] = u_l[tid];
            Pg[b * 64 + tid] = p_l[tid];
            WWg[b * 64 + tid] = ww_l[tid];
        }
    }
}

// ---------------------------------------------------------------------------
extern "C" void kernel_launch(void* const* d_in, const int* in_sizes, int n_in, void* d_out,
                              int out_size, void* d_ws, size_t ws_size, hipStream_t stream) {
    const float* x = (const float*)d_in[0];
    const float* Wih_e = (const float*)d_in[1];
    const float* Whh_e = (const float*)d_in[2];
    const float* b_e = (const float*)d_in[3];
    const float* Wih_c = (const float*)d_in[4];
    const float* Whh_c = (const float*)d_in[5];
    const float* b_c = (const float*)d_in[6];
    float* out = (float*)d_out;
    float* ws = (float*)d_ws;

    int TC = 32;
    while (TC > 2) {
        size_t need = ((size_t)11923392 + (size_t)TC * 325376) * 4;
        if (need <= ws_size) break;
        TC >>= 1;
    }
    const int nch = 256 / TC;
    const int M = TC * 64;

    size_t off = 0;
    float* XPT = ws + off; off += (size_t)2048 * M;
    float* CPT = ws + off; off += (size_t)3036 * M;
    float* Wcat = ws + off; off += (size_t)3036 * 896;
    float* ENC = ws + off; off += (size_t)256 * 64 * 512;
    size_t zoff = off;
    float* HXE = ws + off; off += 2 * 128 * 64 * 4;
    float* CE = ws + off; off += 512 * 64;
    float* HXf = ws + off; off += 2 * 224 * 64 * 4;
    float* CC = ws + off; off += 759 * 64;
    float* Mg = ws + off; off += 64 * 2048;
    float* Ug = ws + off; off += 64 * 64;
    float* Pg = ws + off; off += 64 * 64;
    float* WWg = ws + off; off += 64 * 64;
    float* Lg = ws + off; off += 64 * 4096;
    float* WRg = ws + off; off += 64 * 256;
    int* BAR = (int*)(ws + off); off += (size_t)2 * nch * 512 + 512;
    size_t zbytes = (off - zoff) * 4;

    hipMemsetAsync(ws + zoff, 0, zbytes, stream);
    prep_weights<<<dim3((3036 * 896 + 255) / 256), dim3(256), 0, stream>>>(Whh_c, Wih_c, Wcat);
    for (int c = 0; c < nch; ++c) {
        proj_gemm<<<dim3(32, TC), dim3(256), 0, stream>>>(x, Wih_e, b_e, XPT, 2048, 512, c * TC,
                                                          1, 256, 512, M);
        enc_seq<<<dim3(256), dim3(512), 0, stream>>>(Whh_e, XPT, HXE, CE, ENC, M, c * TC, TC,
                                                     BAR + c * 512);
    }
    for (int c = 0; c < nch; ++c) {
        proj_gemm<<<dim3(48, TC), dim3(256), 0, stream>>>(ENC, Wih_c, b_c, CPT, 3036, 640,
                                                          c * TC * 64, 64, 1, 512, M);
        dnc_seq<<<dim3(256), dim3(1024), 0, stream>>>(Wcat, CPT, HXf, CC, Mg, Ug, Pg, WWg, Lg,
                                                      WRg, out, M, c * TC, TC,
                                                      BAR + (nch + c) * 512);
    }
}

// Round 5
// 8430.411 us; speedup vs baseline: 3.9987x; 3.9987x over previous
//
#include <hip/hip_runtime.h>
#include <math.h>

// ---------------------------------------------------------------------------
// LSTM_DNC round 5: fence-free sequencing.
//  - h/rv communicated via sc0sc1 (agent-scope relaxed atomic) write-through
//    stores to L3; readers use PLAIN float4 loads on per-step slot buffers
//    (each slot written once / read once per dispatch -> no stale caches).
//  - No __threadfence anywhere (no buffer_wbl2/inv): weights stay L2-resident.
//  - Flags: one int per 128B line per block, relaxed agent stores; wave0 polls.
//  - dnc: blocks 64..255 GEMM (4 cells x 4 K-quarters, 1024 thr);
//    blocks 0..63 machinery (batch=bk). Machinery overlapped with next-step
//    K=768 GEMM; rv only feeds the cheap K=128 finish.
// ---------------------------------------------------------------------------

#define EPSF 1e-6f

__device__ __forceinline__ float sigmoidf_(float x) { return 1.f / (1.f + expf(-x)); }
__device__ __forceinline__ float softplusf_(float x) {
    return (x > 0.f) ? x + log1pf(expf(-x)) : log1pf(expf(x));
}
__device__ __forceinline__ void stg_coh(float* p, float v) {
    __hip_atomic_store(p, v, __ATOMIC_RELAXED, __HIP_MEMORY_SCOPE_AGENT);
}
__device__ __forceinline__ void st_flag(int* p, int v) {
    __hip_atomic_store(p, v, __ATOMIC_RELAXED, __HIP_MEMORY_SCOPE_AGENT);
}
__device__ __forceinline__ int ld_flag(const int* p) {
    return __hip_atomic_load(p, __ATOMIC_RELAXED, __HIP_MEMORY_SCOPE_AGENT);
}
// poll all 256 block flags (flag of block i at f[i*32]); call from one wave
__device__ __forceinline__ void poll256(const int* f, int lane, int tgt) {
    const int* p = f + lane * 32;
    for (;;) {
        int a = ld_flag(p);
        int b = ld_flag(p + 64 * 32);
        int c = ld_flag(p + 128 * 32);
        int d = ld_flag(p + 192 * 32);
        if (__all(min(min(a, b), min(c, d)) >= tgt)) break;
        __builtin_amdgcn_s_sleep(2);
    }
}
// poll GEMM block flags (blocks 64..255)
__device__ __forceinline__ void pollg(const int* f, int lane, int tgt) {
    const int* p = f + (64 + lane) * 32;
    for (;;) {
        int a = ld_flag(p);
        int b = ld_flag(p + 64 * 32);
        int c = ld_flag(p + 128 * 32);
        if (__all(min(min(a, b), c) >= tgt)) break;
        __builtin_amdgcn_s_sleep(2);
    }
}
// poll machinery flags (blocks 0..63) at f2[i*32]
__device__ __forceinline__ void pollm(const int* f2, int lane, int tgt) {
    while (!__all(ld_flag(f2 + lane * 32) >= tgt)) __builtin_amdgcn_s_sleep(2);
}

// ---------------------------------------------------------------------------
// prep: Wcat[3036][896]: cols 0..758 = Whh_c, 759..767 = 0, 768..895 = Wih_c rv part
// ---------------------------------------------------------------------------
__global__ __launch_bounds__(256) void prep_weights(const float* __restrict__ Whh_c,
                                                    const float* __restrict__ Wih_c,
                                                    float* __restrict__ Wcat) {
    int idx = blockIdx.x * 256 + threadIdx.x;
    if (idx < 3036 * 896) {
        int r = idx / 896, j = idx - r * 896;
        float v;
        if (j < 759) v = Whh_c[r * 759 + j];
        else if (j < 768) v = 0.f;
        else v = Wih_c[r * 640 + 512 + (j - 768)];
        Wcat[idx] = v;
    }
}

// ---------------------------------------------------------------------------
// proj_gemm: OUT^T[j][m] = bias[j] + sum_{k<512} A[arow(m)][k] * W[j][k]
// ---------------------------------------------------------------------------
__global__ __launch_bounds__(256, 2) void proj_gemm(const float* __restrict__ A,
                                                    const float* __restrict__ W,
                                                    const float* __restrict__ bias,
                                                    float* __restrict__ OUT, int Ncols,
                                                    int wstride, int arow_base, int arow_stride_t,
                                                    int arow_stride_b, int arowlen, int Mrows) {
    __shared__ float As[16 * 68];
    __shared__ float Ws[16 * 68];
    const int tid = threadIdx.x;
    const int ntile = blockIdx.x, mtile = blockIdx.y;
    const int tx = tid & 15, ty = tid >> 4;
    const int lr = tid >> 2;
    const int lk = (tid & 3) * 4;
    const size_t arow =
        (size_t)arow_base + (size_t)mtile * arow_stride_t + (size_t)lr * arow_stride_b;
    const float* aptr = A + arow * arowlen + lk;
    const int wn = ntile * 64 + lr;
    const bool wok = (wn < Ncols);
    const float* wptr = W + (size_t)(wok ? wn : 0) * wstride + lk;
    float acc[4][4] = {};
    for (int kt = 0; kt < 512; kt += 16) {
        float4 av = *(const float4*)(aptr + kt);
        float4 w4l = *(const float4*)(wptr + kt);
        if (!wok) w4l = make_float4(0.f, 0.f, 0.f, 0.f);
        __syncthreads();
        As[(lk + 0) * 68 + lr] = av.x;
        As[(lk + 1) * 68 + lr] = av.y;
        As[(lk + 2) * 68 + lr] = av.z;
        As[(lk + 3) * 68 + lr] = av.w;
        Ws[(lk + 0) * 68 + lr] = w4l.x;
        Ws[(lk + 1) * 68 + lr] = w4l.y;
        Ws[(lk + 2) * 68 + lr] = w4l.z;
        Ws[(lk + 3) * 68 + lr] = w4l.w;
        __syncthreads();
#pragma unroll
        for (int k = 0; k < 16; ++k) {
            float4 a4 = *(const float4*)&As[k * 68 + ty * 4];
            float4 w4 = *(const float4*)&Ws[k * 68 + tx * 4];
            acc[0][0] = fmaf(a4.x, w4.x, acc[0][0]);
            acc[0][1] = fmaf(a4.x, w4.y, acc[0][1]);
            acc[0][2] = fmaf(a4.x, w4.z, acc[0][2]);
            acc[0][3] = fmaf(a4.x, w4.w, acc[0][3]);
            acc[1][0] = fmaf(a4.y, w4.x, acc[1][0]);
            acc[1][1] = fmaf(a4.y, w4.y, acc[1][1]);
            acc[1][2] = fmaf(a4.y, w4.z, acc[1][2]);
            acc[1][3] = fmaf(a4.y, w4.w, acc[1][3]);
            acc[2][0] = fmaf(a4.z, w4.x, acc[2][0]);
            acc[2][1] = fmaf(a4.z, w4.y, acc[2][1]);
            acc[2][2] = fmaf(a4.z, w4.z, acc[2][2]);
            acc[2][3] = fmaf(a4.z, w4.w, acc[2][3]);
            acc[3][0] = fmaf(a4.w, w4.x, acc[3][0]);
            acc[3][1] = fmaf(a4.w, w4.y, acc[3][1]);
            acc[3][2] = fmaf(a4.w, w4.z, acc[3][2]);
            acc[3][3] = fmaf(a4.w, w4.w, acc[3][3]);
        }
    }
    const int col0 = ntile * 64 + tx * 4;
    const int row0 = mtile * 64 + ty * 4;
#pragma unroll
    for (int j = 0; j < 4; ++j) {
        int col = col0 + j;
        if (col < Ncols) {
            float bv = bias[col];
            float4 st = make_float4(acc[0][j] + bv, acc[1][j] + bv, acc[2][j] + bv,
                                    acc[3][j] + bv);
            *(float4*)&OUT[(size_t)col * Mrows + row0] = st;
        }
    }
}

// ---------------------------------------------------------------------------
// enc_seq: 256 blocks x 512 threads; cell = bk + 256*cidx, K-quarter q = wv&3.
// HSE: TC slots of 128 rows x 64 lanes x float4 (32768 floats each).
// Step tl: read slot (tl+TC-1)%TC (plain), write slot tl (sc0sc1), flag, poll.
// ---------------------------------------------------------------------------
__global__ __launch_bounds__(512, 1) void enc_seq(const float* __restrict__ Whh,
                                                  const float* __restrict__ XPT,
                                                  float* __restrict__ HSE,
                                                  float* __restrict__ CE,
                                                  float* __restrict__ ENC, int M, int t0, int TC,
                                                  int* flags) {
    __shared__ float part[8 * 4 * 64];
    const int tid = threadIdx.x;
    const int bk = blockIdx.x;
    const int lane = tid & 63;
    const int wv = __builtin_amdgcn_readfirstlane(tid >> 6);
    const int q = wv & 3, cidx = wv >> 2;
    const int cell = bk + 256 * cidx;
    const float* __restrict__ w0 = Whh + ((size_t)(0 * 512 + cell)) * 512 + q * 128;
    const float* __restrict__ w1 = Whh + ((size_t)(1 * 512 + cell)) * 512 + q * 128;
    const float* __restrict__ w2 = Whh + ((size_t)(2 * 512 + cell)) * 512 + q * 128;
    const float* __restrict__ w3 = Whh + ((size_t)(3 * 512 + cell)) * 512 + q * 128;
    float c_reg = 0.f;
    if (q == 0) c_reg = CE[cell * 64 + lane];
    for (int tl = 0; tl < TC; ++tl) {
        const int t = t0 + tl;
        const float* rslot = HSE + (size_t)((tl + TC - 1) % TC) * 32768;
        float* wslot = HSE + (size_t)tl * 32768;
        float x0 = 0.f, x1 = 0.f, x2 = 0.f, x3 = 0.f;
        if (q == 0) {
            const int m = tl * 64 + lane;
            x0 = XPT[(size_t)(0 * 512 + cell) * M + m];
            x1 = XPT[(size_t)(1 * 512 + cell) * M + m];
            x2 = XPT[(size_t)(2 * 512 + cell) * M + m];
            x3 = XPT[(size_t)(3 * 512 + cell) * M + m];
        }
        float a0 = 0.f, a1 = 0.f, a2 = 0.f, a3 = 0.f;
        {
            const float4* __restrict__ hx = (const float4*)rslot + q * 32 * 64;
#pragma unroll 8
            for (int i = 0; i < 32; ++i) {
                float4 hv = hx[i * 64 + lane];
                float4 q0 = *(const float4*)&w0[i * 4];
                float4 q1 = *(const float4*)&w1[i * 4];
                float4 q2 = *(const float4*)&w2[i * 4];
                float4 q3 = *(const float4*)&w3[i * 4];
                a0 = fmaf(hv.x, q0.x, a0); a0 = fmaf(hv.y, q0.y, a0);
                a0 = fmaf(hv.z, q0.z, a0); a0 = fmaf(hv.w, q0.w, a0);
                a1 = fmaf(hv.x, q1.x, a1); a1 = fmaf(hv.y, q1.y, a1);
                a1 = fmaf(hv.z, q1.z, a1); a1 = fmaf(hv.w, q1.w, a1);
                a2 = fmaf(hv.x, q2.x, a2); a2 = fmaf(hv.y, q2.y, a2);
                a2 = fmaf(hv.z, q2.z, a2); a2 = fmaf(hv.w, q2.w, a2);
                a3 = fmaf(hv.x, q3.x, a3); a3 = fmaf(hv.y, q3.y, a3);
                a3 = fmaf(hv.z, q3.z, a3); a3 = fmaf(hv.w, q3.w, a3);
            }
        }
        part[(wv * 4 + 0) * 64 + lane] = a0;
        part[(wv * 4 + 1) * 64 + lane] = a1;
        part[(wv * 4 + 2) * 64 + lane] = a2;
        part[(wv * 4 + 3) * 64 + lane] = a3;
        __syncthreads();
        if (q == 0) {
            float g4[4];
#pragma unroll
            for (int g = 0; g < 4; ++g) {
                g4[g] = part[((cidx * 4 + 0) * 4 + g) * 64 + lane] +
                        part[((cidx * 4 + 1) * 4 + g) * 64 + lane] +
                        part[((cidx * 4 + 2) * 4 + g) * 64 + lane] +
                        part[((cidx * 4 + 3) * 4 + g) * 64 + lane];
            }
            float cc = sigmoidf_(g4[1] + x1) * c_reg + sigmoidf_(g4[0] + x0) * tanhf(g4[2] + x2);
            float hh = sigmoidf_(g4[3] + x3) * tanhf(cc);
            c_reg = cc;
            stg_coh(&wslot[(cell >> 2) * 256 + lane * 4 + (cell & 3)], hh);
            ENC[((size_t)t * 64 + lane) * 512 + cell] = hh;
        }
        __syncthreads();  // drains vmcnt(0) for all threads before barrier
        if (tid == 0) st_flag(flags + bk * 32, tl + 1);
        if (tl + 1 < TC) {
            if (wv == 0) poll256(flags, lane, tl + 1);
            __syncthreads();
        }
    }
    if (q == 0) CE[cell * 64 + lane] = c_reg;
}

// ---------------------------------------------------------------------------
// dnc_seq: 256 blocks x 1024 threads.
//  blocks 64..255: GEMM, cell = (bk-64) + 192*cidx; blocks 0..63: machinery.
//  HS: TC slots of 224 rows x 64 lanes x float4 (57344 floats each):
//  rows 0..191 = h (k<768), rows 192..223 = rv (k 768..895).
// ---------------------------------------------------------------------------
__global__ __launch_bounds__(1024, 1) void dnc_seq(
    const float* __restrict__ Wcat, const float* __restrict__ CPT, float* __restrict__ HS,
    float* __restrict__ CC, float* __restrict__ Mg, float* __restrict__ Ug,
    float* __restrict__ Pg, float* __restrict__ WWg, float* __restrict__ Lg,
    float* __restrict__ WRg, float* __restrict__ OUT, int M, int t0, int TC, int* flags) {
    __shared__ float part[16 * 4 * 64];
    __shared__ float M_l[64 * 33];
    __shared__ float L_l[64 * 65];
    __shared__ float act[256];
    __shared__ float wr_l[256];
    __shared__ float u_l[64], p_l[64], ww_l[64], cw_l[64], sM2[64], srt_l[64], asrt_l[64];
    __shared__ int rank_l[64];
    __shared__ float modes_l[12], kss_l[4], scal[4];

    const int tid = threadIdx.x;
    const int bk = blockIdx.x;
    const int lane = tid & 63;
    const int wv = __builtin_amdgcn_readfirstlane(tid >> 6);
    const int q = wv & 3, cidx = wv >> 2;
    const bool machb = (bk < 64);
    const int cell = machb ? 0 : (bk - 64) + 192 * cidx;
    const bool valid = !machb && (cell < 759);
    const int b = bk;
    int* flags2 = flags + 8192;

    const float* __restrict__ wh0 = Wcat + (size_t)(0 * 759 + cell) * 896 + q * 192;
    const float* __restrict__ wh1 = Wcat + (size_t)(1 * 759 + cell) * 896 + q * 192;
    const float* __restrict__ wh2 = Wcat + (size_t)(2 * 759 + cell) * 896 + q * 192;
    const float* __restrict__ wh3 = Wcat + (size_t)(3 * 759 + cell) * 896 + q * 192;
    const float* __restrict__ wr0 = Wcat + (size_t)(0 * 759 + cell) * 896 + 768 + q * 32;
    const float* __restrict__ wr1 = Wcat + (size_t)(1 * 759 + cell) * 896 + 768 + q * 32;
    const float* __restrict__ wr2 = Wcat + (size_t)(2 * 759 + cell) * 896 + 768 + q * 32;
    const float* __restrict__ wr3 = Wcat + (size_t)(3 * 759 + cell) * 896 + 768 + q * 32;

    float c_reg = 0.f;
    if (valid && q == 0) c_reg = CC[cell * 64 + lane];

    if (machb) {
        if (tid < 256) {
#pragma unroll
            for (int i = 0; i < 8; ++i) {
                int e = tid + 256 * i;
                M_l[(e >> 5) * 33 + (e & 31)] = Mg[b * 2048 + e];
            }
#pragma unroll
            for (int i = 0; i < 16; ++i) {
                int e = tid + 256 * i;
                L_l[(e >> 6) * 65 + (e & 63)] = Lg[b * 4096 + e];
            }
            wr_l[tid] = WRg[b * 256 + tid];
        }
        if (tid < 64) {
            u_l[tid] = Ug[b * 64 + tid];
            p_l[tid] = Pg[b * 64 + tid];
            ww_l[tid] = WWg[b * 64 + tid];
        }
        __syncthreads();
    }

    float A0 = 0.f, A1 = 0.f, A2 = 0.f, A3 = 0.f;
    if (valid) {  // prologue: acc768 for step t0, h(t0-1) in slot TC-1
        const float4* __restrict__ hx = (const float4*)(HS + (size_t)(TC - 1) * 57344) + q * 48 * 64;
#pragma unroll 8
        for (int i = 0; i < 48; ++i) {
            float4 hv = hx[i * 64 + lane];
            float4 u0 = *(const float4*)&wh0[i * 4];
            float4 u1 = *(const float4*)&wh1[i * 4];
            float4 u2 = *(const float4*)&wh2[i * 4];
            float4 u3 = *(const float4*)&wh3[i * 4];
            A0 = fmaf(hv.x, u0.x, A0); A0 = fmaf(hv.y, u0.y, A0);
            A0 = fmaf(hv.z, u0.z, A0); A0 = fmaf(hv.w, u0.w, A0);
            A1 = fmaf(hv.x, u1.x, A1); A1 = fmaf(hv.y, u1.y, A1);
            A1 = fmaf(hv.z, u1.z, A1); A1 = fmaf(hv.w, u1.w, A1);
            A2 = fmaf(hv.x, u2.x, A2); A2 = fmaf(hv.y, u2.y, A2);
            A2 = fmaf(hv.z, u2.z, A2); A2 = fmaf(hv.w, u2.w, A2);
            A3 = fmaf(hv.x, u3.x, A3); A3 = fmaf(hv.y, u3.y, A3);
            A3 = fmaf(hv.z, u3.z, A3); A3 = fmaf(hv.w, u3.w, A3);
        }
    }

    for (int tl = 0; tl < TC; ++tl) {
        const int t = t0 + tl;
        const bool last = (tl + 1 == TC);
        const float* rslot = HS + (size_t)((tl + TC - 1) % TC) * 57344;
        float* wslot = HS + (size_t)tl * 57344;
        if (!machb) {
            // ---- finish gates: rv(t-1) part (K=128) ----
            float b0 = 0.f, b1 = 0.f, b2 = 0.f, b3 = 0.f;
            float p0 = 0.f, p1 = 0.f, p2 = 0.f, p3 = 0.f;
            if (valid && q == 0) {
                const int m = tl * 64 + lane;
                p0 = CPT[(size_t)(0 * 759 + cell) * M + m];
                p1 = CPT[(size_t)(1 * 759 + cell) * M + m];
                p2 = CPT[(size_t)(2 * 759 + cell) * M + m];
                p3 = CPT[(size_t)(3 * 759 + cell) * M + m];
            }
            if (valid) {
                const float4* __restrict__ hx = (const float4*)rslot + (192 + q * 8) * 64;
#pragma unroll
                for (int i = 0; i < 8; ++i) {
                    float4 hv = hx[i * 64 + lane];
                    float4 u0 = *(const float4*)&wr0[i * 4];
                    float4 u1 = *(const float4*)&wr1[i * 4];
                    float4 u2 = *(const float4*)&wr2[i * 4];
                    float4 u3 = *(const float4*)&wr3[i * 4];
                    b0 = fmaf(hv.x, u0.x, b0); b0 = fmaf(hv.y, u0.y, b0);
                    b0 = fmaf(hv.z, u0.z, b0); b0 = fmaf(hv.w, u0.w, b0);
                    b1 = fmaf(hv.x, u1.x, b1); b1 = fmaf(hv.y, u1.y, b1);
                    b1 = fmaf(hv.z, u1.z, b1); b1 = fmaf(hv.w, u1.w, b1);
                    b2 = fmaf(hv.x, u2.x, b2); b2 = fmaf(hv.y, u2.y, b2);
                    b2 = fmaf(hv.z, u2.z, b2); b2 = fmaf(hv.w, u2.w, b2);
                    b3 = fmaf(hv.x, u3.x, b3); b3 = fmaf(hv.y, u3.y, b3);
                    b3 = fmaf(hv.z, u3.z, b3); b3 = fmaf(hv.w, u3.w, b3);
                }
            }
            part[(wv * 4 + 0) * 64 + lane] = A0 + b0;
            part[(wv * 4 + 1) * 64 + lane] = A1 + b1;
            part[(wv * 4 + 2) * 64 + lane] = A2 + b2;
            part[(wv * 4 + 3) * 64 + lane] = A3 + b3;
            __syncthreads();
            if (valid && q == 0) {
                float g4[4];
#pragma unroll
                for (int g = 0; g < 4; ++g) {
                    g4[g] = part[((cidx * 4 + 0) * 4 + g) * 64 + lane] +
                            part[((cidx * 4 + 1) * 4 + g) * 64 + lane] +
                            part[((cidx * 4 + 2) * 4 + g) * 64 + lane] +
                            part[((cidx * 4 + 3) * 4 + g) * 64 + lane];
                }
                float cc =
                    sigmoidf_(g4[1] + p1) * c_reg + sigmoidf_(g4[0] + p0) * tanhf(g4[2] + p2);
                float hh = sigmoidf_(g4[3] + p3) * tanhf(cc);
                c_reg = cc;
                stg_coh(&wslot[(cell >> 2) * 256 + lane * 4 + (cell & 3)], hh);
                if (cell < 512) OUT[(size_t)lane * 131072 + (size_t)t * 512 + cell] = hh;
            }
            __syncthreads();  // drains vmcnt for all threads
            if (tid == 0) st_flag(flags + bk * 32, tl + 1);
            if (!last) {
                if (wv == 0) pollg(flags, lane, tl + 1);
                __syncthreads();
                // ---- overlap: acc768 for step t+1 from just-published h(t) ----
                A0 = A1 = A2 = A3 = 0.f;
                if (valid) {
                    const float4* __restrict__ hx = (const float4*)wslot + q * 48 * 64;
#pragma unroll 8
                    for (int i = 0; i < 48; ++i) {
                        float4 hv = hx[i * 64 + lane];
                        float4 u0 = *(const float4*)&wh0[i * 4];
                        float4 u1 = *(const float4*)&wh1[i * 4];
                        float4 u2 = *(const float4*)&wh2[i * 4];
                        float4 u3 = *(const float4*)&wh3[i * 4];
                        A0 = fmaf(hv.x, u0.x, A0); A0 = fmaf(hv.y, u0.y, A0);
                        A0 = fmaf(hv.z, u0.z, A0); A0 = fmaf(hv.w, u0.w, A0);
                        A1 = fmaf(hv.x, u1.x, A1); A1 = fmaf(hv.y, u1.y, A1);
                        A1 = fmaf(hv.z, u1.z, A1); A1 = fmaf(hv.w, u1.w, A1);
                        A2 = fmaf(hv.x, u2.x, A2); A2 = fmaf(hv.y, u2.y, A2);
                        A2 = fmaf(hv.z, u2.z, A2); A2 = fmaf(hv.w, u2.w, A2);
                        A3 = fmaf(hv.x, u3.x, A3); A3 = fmaf(hv.y, u3.y, A3);
                        A3 = fmaf(hv.z, u3.z, A3); A3 = fmaf(hv.w, u3.w, A3);
                    }
                }
                if (wv == 0) pollm(flags2, lane, tl + 1);
                __syncthreads();
            }
        } else {
            // ---------------- machinery block (batch = bk) ----------------
            if (wv == 0) pollg(flags, lane, tl + 1);
            __syncthreads();
            if (tid < 247) {
                float v = wslot[(128 + (tid >> 2)) * 256 + b * 4 + (tid & 3)];
                float a;
                if (tid < 128) a = tanhf(v);
                else if (tid < 132) a = softplusf_(v);
                else if (tid < 164) a = tanhf(v);
                else if (tid == 164) a = softplusf_(v);
                else if (tid < 197) a = sigmoidf_(v);
                else if (tid < 229) a = tanhf(v);
                else if (tid < 235) a = sigmoidf_(v);
                else a = v;
                act[tid] = a;
            }
            __syncthreads();
            if (tid < 4) {
                float m0 = act[235 + 3 * tid], m1 = act[236 + 3 * tid], m2 = act[237 + 3 * tid];
                float mx = fmaxf(m0, fmaxf(m1, m2));
                float e0 = expf(m0 - mx), e1 = expf(m1 - mx), e2 = expf(m2 - mx);
                float s = e0 + e1 + e2;
                modes_l[3 * tid] = e0 / s;
                modes_l[3 * tid + 1] = e1 / s;
                modes_l[3 * tid + 2] = e2 / s;
                float ks = 0.f;
                for (int w = 0; w < 32; ++w) {
                    float kk = act[tid * 32 + w];
                    ks = fmaf(kk, kk, ks);
                }
                kss_l[tid] = ks;
            }
            if (tid == 64) {
                float s = 0.f;
                for (int w = 0; w < 32; ++w) {
                    float kk = act[132 + w];
                    s = fmaf(kk, kk, s);
                }
                scal[0] = s;
            }
            if (tid < 64) {
                float psi = 1.f;
#pragma unroll
                for (int r = 0; r < 4; ++r) psi *= 1.f - act[229 + r] * wr_l[r * 64 + tid];
                float un = u_l[tid], wwn = ww_l[tid];
                u_l[tid] = (un + wwn - un * wwn) * psi;
                float s2 = 0.f;
                for (int w = 0; w < 32; ++w) {
                    float mm = M_l[tid * 33 + w];
                    s2 = fmaf(mm, mm, s2);
                }
                sM2[tid] = s2;
            }
            __syncthreads();
            if (tid < 64) {
                float un = u_l[tid];
                int rk = 0;
                for (int m = 0; m < 64; ++m) {
                    float um = u_l[m];
                    rk += (um < un) || (um == un && m < tid);
                }
                srt_l[rk] = un;
                rank_l[tid] = rk;
            }
            __syncthreads();
            if (tid < 64) {
                float v = srt_l[tid];
                float incl = v;
#pragma unroll
                for (int off = 1; off < 64; off <<= 1) {
                    float o = __shfl_up(incl, off);
                    if (tid >= off) incl *= o;
                }
                float excl = __shfl_up(incl, 1);
                if (tid == 0) excl = 1.f;
                asrt_l[tid] = (1.f - v) * excl;
                float dot = 0.f;
                for (int w = 0; w < 32; ++w) dot = fmaf(act[132 + w], M_l[tid * 33 + w], dot);
                float logit = dot * rsqrtf(sM2[tid] + EPSF) * rsqrtf(scal[0] + EPSF) * act[164];
                float mx = logit;
#pragma unroll
                for (int off = 32; off; off >>= 1) mx = fmaxf(mx, __shfl_xor(mx, off));
                float e = expf(logit - mx);
                float s = e;
#pragma unroll
                for (int off = 32; off; off >>= 1) s += __shfl_xor(s, off);
                cw_l[tid] = e / s;
            }
            __syncthreads();
            if (tid < 64) {
                float a = asrt_l[rank_l[tid]];
                float agv = act[233], wgv = act[234];
                float wn = wgv * (agv * a + (1.f - agv) * cw_l[tid]);
                ww_l[tid] = wn;
                float s = wn;
#pragma unroll
                for (int off = 32; off; off >>= 1) s += __shfl_xor(s, off);
                if (tid == 0) scal[1] = s;
            }
            __syncthreads();
            if (tid < 256) {
#pragma unroll
                for (int i = 0; i < 8; ++i) {
                    int e = tid + 256 * i;
                    int n = e >> 5, w = e & 31;
                    float wwn = ww_l[n];
                    M_l[n * 33 + w] =
                        M_l[n * 33 + w] * (1.f - wwn * act[165 + w]) + wwn * act[197 + w];
                }
#pragma unroll
                for (int i = 0; i < 16; ++i) {
                    int e = tid + 256 * i;
                    int n = e >> 6, m = e & 63;
                    float Lv = L_l[n * 65 + m];
                    Lv = (1.f - ww_l[n] - ww_l[m]) * Lv + ww_l[n] * p_l[m];
                    L_l[n * 65 + m] = (n == m) ? 0.f : Lv;
                }
            }
            __syncthreads();
            if (tid < 64) {
                p_l[tid] = (1.f - scal[1]) * p_l[tid] + ww_l[tid];
                float s2 = 0.f;
                for (int w = 0; w < 32; ++w) {
                    float mm = M_l[tid * 33 + w];
                    s2 = fmaf(mm, mm, s2);
                }
                sM2[tid] = s2;
            }
            __syncthreads();
            float wrn = 0.f;
            if (tid < 256) {
                const int r = wv;
                const int n = lane;
                float dot = 0.f;
                for (int w = 0; w < 32; ++w) dot = fmaf(act[r * 32 + w], M_l[n * 33 + w], dot);
                float logit = dot * rsqrtf(sM2[n] + EPSF) * rsqrtf(kss_l[r] + EPSF) * act[128 + r];
                float mx = logit;
#pragma unroll
                for (int off = 32; off; off >>= 1) mx = fmaxf(mx, __shfl_xor(mx, off));
                float e = expf(logit - mx);
                float s = e;
#pragma unroll
                for (int off = 32; off; off >>= 1) s += __shfl_xor(s, off);
                float cr = e / s;
                float fw = 0.f, bw = 0.f;
                for (int m = 0; m < 64; ++m) {
                    float wrm = wr_l[r * 64 + m];
                    fw = fmaf(L_l[n * 65 + m], wrm, fw);
                    bw = fmaf(L_l[m * 65 + n], wrm, bw);
                }
                wrn = modes_l[r * 3] * bw + modes_l[r * 3 + 1] * cr + modes_l[r * 3 + 2] * fw;
            }
            __syncthreads();
            if (tid < 256) wr_l[tid] = wrn;
            __syncthreads();
            if (tid < 128) {
                const int r = tid >> 5, w = tid & 31;
                float rv = 0.f;
                for (int n = 0; n < 64; ++n) rv = fmaf(wr_l[r * 64 + n], M_l[n * 33 + w], rv);
                stg_coh(&wslot[(192 + (tid >> 2)) * 256 + b * 4 + (tid & 3)], rv);
            }
            __syncthreads();  // drains vmcnt
            if (tid == 0) st_flag(flags2 + bk * 32, tl + 1);
        }
    }
    if (valid && q == 0) CC[cell * 64 + lane] = c_reg;
    if (machb) {
        if (tid < 256) {
#pragma unroll
            for (int i = 0; i < 8; ++i) {
                int e = tid + 256 * i;
                Mg[b * 2048 + e] = M_l[(e >> 5) * 33 + (e & 31)];
            }
#pragma unroll
            for (int i = 0; i < 16; ++i) {
                int e = tid + 256 * i;
                Lg[b * 4096 + e] = L_l[(e >> 6) * 65 + (e & 63)];
            }
            WRg[b * 256 + tid] = wr_l[tid];
        }
        if (tid < 64) {
            Ug[b * 64 + tid] = u_l[tid];
            Pg[b * 64 + tid] = p_l[tid];
            WWg[b * 64 + tid] = ww_l[tid];
        }
    }
}

// ---------------------------------------------------------------------------
extern "C" void kernel_launch(void* const* d_in, const int* in_sizes, int n_in, void* d_out,
                              int out_size, void* d_ws, size_t ws_size, hipStream_t stream) {
    const float* x = (const float*)d_in[0];
    const float* Wih_e = (const float*)d_in[1];
    const float* Whh_e = (const float*)d_in[2];
    const float* b_e = (const float*)d_in[3];
    const float* Wih_c = (const float*)d_in[4];
    const float* Whh_c = (const float*)d_in[5];
    const float* b_c = (const float*)d_in[6];
    float* out = (float*)d_out;
    float* ws = (float*)d_ws;

    int TC = 32;
    while (TC > 2) {
        size_t need =
            ((size_t)11612096 + (size_t)TC * 415488 + (size_t)(512 / TC) * 16384) * 4;
        if (need <= ws_size) break;
        TC >>= 1;
    }
    const int nch = 256 / TC;
    const int M = TC * 64;

    size_t off = 0;
    float* XPT = ws + off; off += (size_t)2048 * M;
    float* CPT = ws + off; off += (size_t)3036 * M;
    float* Wcat = ws + off; off += (size_t)3036 * 896;
    float* ENC = ws + off; off += (size_t)256 * 64 * 512;
    size_t zoff = off;
    float* HSE = ws + off; off += (size_t)TC * 32768;  // enc h slots
    float* CE = ws + off; off += 512 * 64;
    float* HS = ws + off; off += (size_t)TC * 57344;   // dnc h/rv slots
    float* CC = ws + off; off += 759 * 64;
    float* Mg = ws + off; off += 64 * 2048;
    float* Ug = ws + off; off += 64 * 64;
    float* Pg = ws + off; off += 64 * 64;
    float* WWg = ws + off; off += 64 * 64;
    float* Lg = ws + off; off += 64 * 4096;
    float* WRg = ws + off; off += 64 * 256;
    int* BAR = (int*)(ws + off); off += (size_t)2 * nch * 16384;
    size_t zbytes = (off - zoff) * 4;

    hipMemsetAsync(ws + zoff, 0, zbytes, stream);
    prep_weights<<<dim3((3036 * 896 + 255) / 256), dim3(256), 0, stream>>>(Whh_c, Wih_c, Wcat);
    for (int c = 0; c < nch; ++c) {
        proj_gemm<<<dim3(32, TC), dim3(256), 0, stream>>>(x, Wih_e, b_e, XPT, 2048, 512, c * TC,
                                                          1, 256, 512, M);
        enc_seq<<<dim3(256), dim3(512), 0, stream>>>(Whh_e, XPT, HSE, CE, ENC, M, c * TC, TC,
                                                     BAR + (size_t)c * 16384);
    }
    for (int c = 0; c < nch; ++c) {
        proj_gemm<<<dim3(48, TC), dim3(256), 0, stream>>>(ENC, Wih_c, b_c, CPT, 3036, 640,
                                                          c * TC * 64, 64, 1, 512, M);
        dnc_seq<<<dim3(256), dim3(1024), 0, stream>>>(Wcat, CPT, HS, CC, Mg, Ug, Pg, WWg, Lg,
                                                      WRg, out, M, c * TC, TC,
                                                      BAR + (size_t)(nch + c) * 16384);
    }
}

// Round 6
// 8098.793 us; speedup vs baseline: 4.1625x; 1.0409x over previous
//
#include <hip/hip_runtime.h>
#include <math.h>

// ---------------------------------------------------------------------------
// LSTM_DNC round 6: critical-path trim.
//  - No OUT/ENC stores inside the sequenced kernels: h lives in rotating slots,
//    bulk emit kernels produce the row-major outputs afterwards.
//  - Machinery: 7 sync phases (wave0 runs the serial chain wave-synchronously).
//  - cidx-major cell map: xi cells (512..758) in blocks 192..253; machinery
//    polls only those 62 flags.
//  - CPT bias prefetched one step ahead during the overlapped K=768 GEMM.
//  - Fence-free sc0sc1 publish + slot rotation (R5 scheme) retained.
// ---------------------------------------------------------------------------

#define EPSF 1e-6f

__device__ __forceinline__ float sigmoidf_(float x) { return 1.f / (1.f + expf(-x)); }
__device__ __forceinline__ float softplusf_(float x) {
    return (x > 0.f) ? x + log1pf(expf(-x)) : log1pf(expf(x));
}
__device__ __forceinline__ void stg_coh(float* p, float v) {
    __hip_atomic_store(p, v, __ATOMIC_RELAXED, __HIP_MEMORY_SCOPE_AGENT);
}
__device__ __forceinline__ void st_flag(int* p, int v) {
    __hip_atomic_store(p, v, __ATOMIC_RELAXED, __HIP_MEMORY_SCOPE_AGENT);
}
__device__ __forceinline__ int ld_flag(const int* p) {
    return __hip_atomic_load(p, __ATOMIC_RELAXED, __HIP_MEMORY_SCOPE_AGENT);
}
// poll all 256 block flags (block i flag at f[i*32]); one wave
__device__ __forceinline__ void poll256(const int* f, int lane, int tgt) {
    const int* p = f + lane * 32;
    for (;;) {
        int a = ld_flag(p);
        int b = ld_flag(p + 64 * 32);
        int c = ld_flag(p + 128 * 32);
        int d = ld_flag(p + 192 * 32);
        if (__all(min(min(a, b), min(c, d)) >= tgt)) break;
        __builtin_amdgcn_s_sleep(2);
    }
}
// poll GEMM block flags (blocks 64..255); one wave
__device__ __forceinline__ void pollg(const int* f, int lane, int tgt) {
    const int* p = f + (64 + lane) * 32;
    for (;;) {
        int a = ld_flag(p);
        int b = ld_flag(p + 64 * 32);
        int c = ld_flag(p + 128 * 32);
        if (__all(min(min(a, b), c) >= tgt)) break;
        __builtin_amdgcn_s_sleep(2);
    }
}
// poll xi-cell blocks (192..253); one wave
__device__ __forceinline__ void pollx(const int* f, int lane, int tgt) {
    const int* p = f + (192 + (lane < 62 ? lane : 61)) * 32;
    while (!__all(ld_flag(p) >= tgt)) __builtin_amdgcn_s_sleep(2);
}
// poll machinery flags (blocks 0..63) at f2[i*32]; one wave
__device__ __forceinline__ void pollm(const int* f2, int lane, int tgt) {
    while (!__all(ld_flag(f2 + lane * 32) >= tgt)) __builtin_amdgcn_s_sleep(2);
}

// ---------------------------------------------------------------------------
__global__ __launch_bounds__(256) void prep_weights(const float* __restrict__ Whh_c,
                                                    const float* __restrict__ Wih_c,
                                                    float* __restrict__ Wcat) {
    int idx = blockIdx.x * 256 + threadIdx.x;
    if (idx < 3036 * 896) {
        int r = idx / 896, j = idx - r * 896;
        float v;
        if (j < 759) v = Whh_c[r * 759 + j];
        else if (j < 768) v = 0.f;
        else v = Wih_c[r * 640 + 512 + (j - 768)];
        Wcat[idx] = v;
    }
}

// ---------------------------------------------------------------------------
// proj_gemm: OUT^T[j][m] = bias[j] + sum_{k<512} A[arow(m)][k] * W[j][k]
// ---------------------------------------------------------------------------
__global__ __launch_bounds__(256, 2) void proj_gemm(const float* __restrict__ A,
                                                    const float* __restrict__ W,
                                                    const float* __restrict__ bias,
                                                    float* __restrict__ OUT, int Ncols,
                                                    int wstride, int arow_base, int arow_stride_t,
                                                    int arow_stride_b, int arowlen, int Mrows) {
    __shared__ float As[16 * 68];
    __shared__ float Ws[16 * 68];
    const int tid = threadIdx.x;
    const int ntile = blockIdx.x, mtile = blockIdx.y;
    const int tx = tid & 15, ty = tid >> 4;
    const int lr = tid >> 2;
    const int lk = (tid & 3) * 4;
    const size_t arow =
        (size_t)arow_base + (size_t)mtile * arow_stride_t + (size_t)lr * arow_stride_b;
    const float* aptr = A + arow * arowlen + lk;
    const int wn = ntile * 64 + lr;
    const bool wok = (wn < Ncols);
    const float* wptr = W + (size_t)(wok ? wn : 0) * wstride + lk;
    float acc[4][4] = {};
    for (int kt = 0; kt < 512; kt += 16) {
        float4 av = *(const float4*)(aptr + kt);
        float4 w4l = *(const float4*)(wptr + kt);
        if (!wok) w4l = make_float4(0.f, 0.f, 0.f, 0.f);
        __syncthreads();
        As[(lk + 0) * 68 + lr] = av.x;
        As[(lk + 1) * 68 + lr] = av.y;
        As[(lk + 2) * 68 + lr] = av.z;
        As[(lk + 3) * 68 + lr] = av.w;
        Ws[(lk + 0) * 68 + lr] = w4l.x;
        Ws[(lk + 1) * 68 + lr] = w4l.y;
        Ws[(lk + 2) * 68 + lr] = w4l.z;
        Ws[(lk + 3) * 68 + lr] = w4l.w;
        __syncthreads();
#pragma unroll
        for (int k = 0; k < 16; ++k) {
            float4 a4 = *(const float4*)&As[k * 68 + ty * 4];
            float4 w4 = *(const float4*)&Ws[k * 68 + tx * 4];
            acc[0][0] = fmaf(a4.x, w4.x, acc[0][0]);
            acc[0][1] = fmaf(a4.x, w4.y, acc[0][1]);
            acc[0][2] = fmaf(a4.x, w4.z, acc[0][2]);
            acc[0][3] = fmaf(a4.x, w4.w, acc[0][3]);
            acc[1][0] = fmaf(a4.y, w4.x, acc[1][0]);
            acc[1][1] = fmaf(a4.y, w4.y, acc[1][1]);
            acc[1][2] = fmaf(a4.y, w4.z, acc[1][2]);
            acc[1][3] = fmaf(a4.y, w4.w, acc[1][3]);
            acc[2][0] = fmaf(a4.z, w4.x, acc[2][0]);
            acc[2][1] = fmaf(a4.z, w4.y, acc[2][1]);
            acc[2][2] = fmaf(a4.z, w4.z, acc[2][2]);
            acc[2][3] = fmaf(a4.z, w4.w, acc[2][3]);
            acc[3][0] = fmaf(a4.w, w4.x, acc[3][0]);
            acc[3][1] = fmaf(a4.w, w4.y, acc[3][1]);
            acc[3][2] = fmaf(a4.w, w4.z, acc[3][2]);
            acc[3][3] = fmaf(a4.w, w4.w, acc[3][3]);
        }
    }
    const int col0 = ntile * 64 + tx * 4;
    const int row0 = mtile * 64 + ty * 4;
#pragma unroll
    for (int j = 0; j < 4; ++j) {
        int col = col0 + j;
        if (col < Ncols) {
            float bv = bias[col];
            float4 st = make_float4(acc[0][j] + bv, acc[1][j] + bv, acc[2][j] + bv,
                                    acc[3][j] + bv);
            *(float4*)&OUT[(size_t)col * Mrows + row0] = st;
        }
    }
}

// ---------------------------------------------------------------------------
// emit kernels: slot layout [k4*256 + b*4 + k&3] -> row-major outputs (bulk).
// enc_emit: ENC[(t*64+b)*512 + c]; out_emit: OUT[b*131072 + t*512 + c]
// grid: (TC, 32) blocks x 256 thr; thread: c4 = tid&127, b = bgrp*2 + (tid>>7)
// ---------------------------------------------------------------------------
__global__ __launch_bounds__(256) void enc_emit(const float* __restrict__ HSE,
                                                float* __restrict__ ENC, int t0) {
    const int tl = blockIdx.x, bgrp = blockIdx.y;
    const int c4 = threadIdx.x & 127, b = bgrp * 2 + (threadIdx.x >> 7);
    float4 v = *(const float4*)&HSE[(size_t)tl * 32768 + c4 * 256 + b * 4];
    *(float4*)&ENC[((size_t)(t0 + tl) * 64 + b) * 512 + c4 * 4] = v;
}
__global__ __launch_bounds__(256) void out_emit(const float* __restrict__ HS,
                                                float* __restrict__ OUT, int t0) {
    const int tl = blockIdx.x, bgrp = blockIdx.y;
    const int c4 = threadIdx.x & 127, b = bgrp * 2 + (threadIdx.x >> 7);
    float4 v = *(const float4*)&HS[(size_t)tl * 57344 + c4 * 256 + b * 4];
    *(float4*)&OUT[(size_t)b * 131072 + (size_t)(t0 + tl) * 512 + c4 * 4] = v;
}

// ---------------------------------------------------------------------------
// enc_seq: 256 blocks x 512 threads; cell = bk + 256*cidx, K-quarter q = wv&3.
// HSE: TC slots of 128 rows x 64 lanes x float4.
// ---------------------------------------------------------------------------
__global__ __launch_bounds__(512, 1) void enc_seq(const float* __restrict__ Whh,
                                                  const float* __restrict__ XPT,
                                                  float* __restrict__ HSE,
                                                  float* __restrict__ CE, int M, int TC,
                                                  int* flags) {
    __shared__ float part[8 * 4 * 64];
    const int tid = threadIdx.x;
    const int bk = blockIdx.x;
    const int lane = tid & 63;
    const int wv = __builtin_amdgcn_readfirstlane(tid >> 6);
    const int q = wv & 3, cidx = wv >> 2;
    const int cell = bk + 256 * cidx;
    const float* __restrict__ w0 = Whh + ((size_t)(0 * 512 + cell)) * 512 + q * 128;
    const float* __restrict__ w1 = Whh + ((size_t)(1 * 512 + cell)) * 512 + q * 128;
    const float* __restrict__ w2 = Whh + ((size_t)(2 * 512 + cell)) * 512 + q * 128;
    const float* __restrict__ w3 = Whh + ((size_t)(3 * 512 + cell)) * 512 + q * 128;
    float c_reg = 0.f;
    if (q == 0) c_reg = CE[cell * 64 + lane];
    for (int tl = 0; tl < TC; ++tl) {
        const float* rslot = HSE + (size_t)((tl + TC - 1) % TC) * 32768;
        float* wslot = HSE + (size_t)tl * 32768;
        float x0 = 0.f, x1 = 0.f, x2 = 0.f, x3 = 0.f;
        if (q == 0) {
            const int m = tl * 64 + lane;
            x0 = XPT[(size_t)(0 * 512 + cell) * M + m];
            x1 = XPT[(size_t)(1 * 512 + cell) * M + m];
            x2 = XPT[(size_t)(2 * 512 + cell) * M + m];
            x3 = XPT[(size_t)(3 * 512 + cell) * M + m];
        }
        float a0 = 0.f, a1 = 0.f, a2 = 0.f, a3 = 0.f;
        {
            const float4* __restrict__ hx = (const float4*)rslot + q * 32 * 64;
#pragma unroll 8
            for (int i = 0; i < 32; ++i) {
                float4 hv = hx[i * 64 + lane];
                float4 q0 = *(const float4*)&w0[i * 4];
                float4 q1 = *(const float4*)&w1[i * 4];
                float4 q2 = *(const float4*)&w2[i * 4];
                float4 q3 = *(const float4*)&w3[i * 4];
                a0 = fmaf(hv.x, q0.x, a0); a0 = fmaf(hv.y, q0.y, a0);
                a0 = fmaf(hv.z, q0.z, a0); a0 = fmaf(hv.w, q0.w, a0);
                a1 = fmaf(hv.x, q1.x, a1); a1 = fmaf(hv.y, q1.y, a1);
                a1 = fmaf(hv.z, q1.z, a1); a1 = fmaf(hv.w, q1.w, a1);
                a2 = fmaf(hv.x, q2.x, a2); a2 = fmaf(hv.y, q2.y, a2);
                a2 = fmaf(hv.z, q2.z, a2); a2 = fmaf(hv.w, q2.w, a2);
                a3 = fmaf(hv.x, q3.x, a3); a3 = fmaf(hv.y, q3.y, a3);
                a3 = fmaf(hv.z, q3.z, a3); a3 = fmaf(hv.w, q3.w, a3);
            }
        }
        part[(wv * 4 + 0) * 64 + lane] = a0;
        part[(wv * 4 + 1) * 64 + lane] = a1;
        part[(wv * 4 + 2) * 64 + lane] = a2;
        part[(wv * 4 + 3) * 64 + lane] = a3;
        __syncthreads();
        if (q == 0) {
            float g4[4];
#pragma unroll
            for (int g = 0; g < 4; ++g) {
                g4[g] = part[((cidx * 4 + 0) * 4 + g) * 64 + lane] +
                        part[((cidx * 4 + 1) * 4 + g) * 64 + lane] +
                        part[((cidx * 4 + 2) * 4 + g) * 64 + lane] +
                        part[((cidx * 4 + 3) * 4 + g) * 64 + lane];
            }
            float cc = sigmoidf_(g4[1] + x1) * c_reg + sigmoidf_(g4[0] + x0) * tanhf(g4[2] + x2);
            float hh = sigmoidf_(g4[3] + x3) * tanhf(cc);
            c_reg = cc;
            stg_coh(&wslot[(cell >> 2) * 256 + lane * 4 + (cell & 3)], hh);
        }
        __syncthreads();  // drains vmcnt before flag
        if (tid == 0) st_flag(flags + bk * 32, tl + 1);
        if (tl + 1 < TC) {
            if (wv == 0) poll256(flags, lane, tl + 1);
            __syncthreads();
        }
    }
    if (q == 0) CE[cell * 64 + lane] = c_reg;
}

// ---------------------------------------------------------------------------
// dnc_seq: 256 blocks x 1024 threads.
//  blocks 64..253: GEMM, cell = (bk-64)*4 + cidx (cidx=wv>>2, q=wv&3).
//  blocks 0..63: machinery (batch=bk). HS: TC slots of 224 rows x 64 x float4;
//  rows 0..191 = h, rows 192..223 = rv.
// ---------------------------------------------------------------------------
__global__ __launch_bounds__(1024, 1) void dnc_seq(
    const float* __restrict__ Wcat, const float* __restrict__ CPT, float* __restrict__ HS,
    float* __restrict__ CC, float* __restrict__ Mg, float* __restrict__ Ug,
    float* __restrict__ Pg, float* __restrict__ WWg, float* __restrict__ Lg,
    float* __restrict__ WRg, int M, int TC, int* flags) {
    __shared__ float part[16 * 4 * 64];
    __shared__ float M_l[64 * 33];
    __shared__ float L_l[64 * 65];
    __shared__ float act[256];
    __shared__ float wr_l[256];
    __shared__ float u_l[64], p_l[64], ww_l[64], sM2[64], srt_l[64], asrt_l[64];
    __shared__ float modes_l[12], kss_l[4], scal[4];

    const int tid = threadIdx.x;
    const int bk = blockIdx.x;
    const int lane = tid & 63;
    const int wv = __builtin_amdgcn_readfirstlane(tid >> 6);
    const int q = wv & 3, cidx = wv >> 2;
    const bool machb = (bk < 64);
    const int cell_raw = machb ? 0 : (bk - 64) * 4 + cidx;
    const bool valid = !machb && (cell_raw < 759);
    const int cell = valid ? cell_raw : 0;
    const int b = bk;
    int* flags2 = flags + 8192;

    const float* __restrict__ wh0 = Wcat + (size_t)(0 * 759 + cell) * 896 + q * 192;
    const float* __restrict__ wh1 = Wcat + (size_t)(1 * 759 + cell) * 896 + q * 192;
    const float* __restrict__ wh2 = Wcat + (size_t)(2 * 759 + cell) * 896 + q * 192;
    const float* __restrict__ wh3 = Wcat + (size_t)(3 * 759 + cell) * 896 + q * 192;
    const float* __restrict__ wr0 = Wcat + (size_t)(0 * 759 + cell) * 896 + 768 + q * 32;
    const float* __restrict__ wr1 = Wcat + (size_t)(1 * 759 + cell) * 896 + 768 + q * 32;
    const float* __restrict__ wr2 = Wcat + (size_t)(2 * 759 + cell) * 896 + 768 + q * 32;
    const float* __restrict__ wr3 = Wcat + (size_t)(3 * 759 + cell) * 896 + 768 + q * 32;

    float c_reg = 0.f;
    if (valid && q == 0) c_reg = CC[cell * 64 + lane];

    if (machb) {
        if (tid < 256) {
#pragma unroll
            for (int i = 0; i < 8; ++i) {
                int e = tid + 256 * i;
                M_l[(e >> 5) * 33 + (e & 31)] = Mg[b * 2048 + e];
            }
#pragma unroll
            for (int i = 0; i < 16; ++i) {
                int e = tid + 256 * i;
                L_l[(e >> 6) * 65 + (e & 63)] = Lg[b * 4096 + e];
            }
            wr_l[tid] = WRg[b * 256 + tid];
        }
        if (tid < 64) {
            u_l[tid] = Ug[b * 64 + tid];
            p_l[tid] = Pg[b * 64 + tid];
            ww_l[tid] = WWg[b * 64 + tid];
        }
        __syncthreads();
    }

    // prologue: CPT(0) preload + acc768 for step 0 from slot TC-1
    float cp0 = 0.f, cp1 = 0.f, cp2 = 0.f, cp3 = 0.f;
    if (valid && q == 0) {
        cp0 = CPT[(size_t)(0 * 759 + cell) * M + lane];
        cp1 = CPT[(size_t)(1 * 759 + cell) * M + lane];
        cp2 = CPT[(size_t)(2 * 759 + cell) * M + lane];
        cp3 = CPT[(size_t)(3 * 759 + cell) * M + lane];
    }
    float A0 = 0.f, A1 = 0.f, A2 = 0.f, A3 = 0.f;
    if (valid) {
        const float4* __restrict__ hx = (const float4*)(HS + (size_t)(TC - 1) * 57344) + q * 48 * 64;
#pragma unroll 8
        for (int i = 0; i < 48; ++i) {
            float4 hv = hx[i * 64 + lane];
            float4 u0 = *(const float4*)&wh0[i * 4];
            float4 u1 = *(const float4*)&wh1[i * 4];
            float4 u2 = *(const float4*)&wh2[i * 4];
            float4 u3 = *(const float4*)&wh3[i * 4];
            A0 = fmaf(hv.x, u0.x, A0); A0 = fmaf(hv.y, u0.y, A0);
            A0 = fmaf(hv.z, u0.z, A0); A0 = fmaf(hv.w, u0.w, A0);
            A1 = fmaf(hv.x, u1.x, A1); A1 = fmaf(hv.y, u1.y, A1);
            A1 = fmaf(hv.z, u1.z, A1); A1 = fmaf(hv.w, u1.w, A1);
            A2 = fmaf(hv.x, u2.x, A2); A2 = fmaf(hv.y, u2.y, A2);
            A2 = fmaf(hv.z, u2.z, A2); A2 = fmaf(hv.w, u2.w, A2);
            A3 = fmaf(hv.x, u3.x, A3); A3 = fmaf(hv.y, u3.y, A3);
            A3 = fmaf(hv.z, u3.z, A3); A3 = fmaf(hv.w, u3.w, A3);
        }
    }

    for (int tl = 0; tl < TC; ++tl) {
        const bool last = (tl + 1 == TC);
        const float* rslot = HS + (size_t)((tl + TC - 1) % TC) * 57344;
        float* wslot = HS + (size_t)tl * 57344;
        if (!machb) {
            // ---- finish gates: rv(t-1) part (K=128) ----
            float b0 = 0.f, b1 = 0.f, b2 = 0.f, b3 = 0.f;
            if (valid) {
                const float4* __restrict__ hx = (const float4*)rslot + (192 + q * 8) * 64;
#pragma unroll
                for (int i = 0; i < 8; ++i) {
                    float4 hv = hx[i * 64 + lane];
                    float4 u0 = *(const float4*)&wr0[i * 4];
                    float4 u1 = *(const float4*)&wr1[i * 4];
                    float4 u2 = *(const float4*)&wr2[i * 4];
                    float4 u3 = *(const float4*)&wr3[i * 4];
                    b0 = fmaf(hv.x, u0.x, b0); b0 = fmaf(hv.y, u0.y, b0);
                    b0 = fmaf(hv.z, u0.z, b0); b0 = fmaf(hv.w, u0.w, b0);
                    b1 = fmaf(hv.x, u1.x, b1); b1 = fmaf(hv.y, u1.y, b1);
                    b1 = fmaf(hv.z, u1.z, b1); b1 = fmaf(hv.w, u1.w, b1);
                    b2 = fmaf(hv.x, u2.x, b2); b2 = fmaf(hv.y, u2.y, b2);
                    b2 = fmaf(hv.z, u2.z, b2); b2 = fmaf(hv.w, u2.w, b2);
                    b3 = fmaf(hv.x, u3.x, b3); b3 = fmaf(hv.y, u3.y, b3);
                    b3 = fmaf(hv.z, u3.z, b3); b3 = fmaf(hv.w, u3.w, b3);
                }
            }
            part[(wv * 4 + 0) * 64 + lane] = A0 + b0;
            part[(wv * 4 + 1) * 64 + lane] = A1 + b1;
            part[(wv * 4 + 2) * 64 + lane] = A2 + b2;
            part[(wv * 4 + 3) * 64 + lane] = A3 + b3;
            __syncthreads();
            if (valid && q == 0) {
                float g4[4];
#pragma unroll
                for (int g = 0; g < 4; ++g) {
                    g4[g] = part[((cidx * 4 + 0) * 4 + g) * 64 + lane] +
                            part[((cidx * 4 + 1) * 4 + g) * 64 + lane] +
                            part[((cidx * 4 + 2) * 4 + g) * 64 + lane] +
                            part[((cidx * 4 + 3) * 4 + g) * 64 + lane];
                }
                float cc =
                    sigmoidf_(g4[1] + cp1) * c_reg + sigmoidf_(g4[0] + cp0) * tanhf(g4[2] + cp2);
                float hh = sigmoidf_(g4[3] + cp3) * tanhf(cc);
                c_reg = cc;
                stg_coh(&wslot[(bk - 64) * 256 + lane * 4 + cidx], hh);
            }
            __syncthreads();  // drains vmcnt for all threads
            if (tid == 0) st_flag(flags + bk * 32, tl + 1);
            if (!last) {
                if (wv == 0) pollg(flags, lane, tl + 1);
                __syncthreads();
                // prefetch CPT(tl+1) — in flight during acc768
                float np0 = 0.f, np1 = 0.f, np2 = 0.f, np3 = 0.f;
                if (valid && q == 0) {
                    const int m = (tl + 1) * 64 + lane;
                    np0 = CPT[(size_t)(0 * 759 + cell) * M + m];
                    np1 = CPT[(size_t)(1 * 759 + cell) * M + m];
                    np2 = CPT[(size_t)(2 * 759 + cell) * M + m];
                    np3 = CPT[(size_t)(3 * 759 + cell) * M + m];
                }
                // overlap: acc768 for step t+1 from just-published h(t)
                A0 = A1 = A2 = A3 = 0.f;
                if (valid) {
                    const float4* __restrict__ hx = (const float4*)wslot + q * 48 * 64;
#pragma unroll 8
                    for (int i = 0; i < 48; ++i) {
                        float4 hv = hx[i * 64 + lane];
                        float4 u0 = *(const float4*)&wh0[i * 4];
                        float4 u1 = *(const float4*)&wh1[i * 4];
                        float4 u2 = *(const float4*)&wh2[i * 4];
                        float4 u3 = *(const float4*)&wh3[i * 4];
                        A0 = fmaf(hv.x, u0.x, A0); A0 = fmaf(hv.y, u0.y, A0);
                        A0 = fmaf(hv.z, u0.z, A0); A0 = fmaf(hv.w, u0.w, A0);
                        A1 = fmaf(hv.x, u1.x, A1); A1 = fmaf(hv.y, u1.y, A1);
                        A1 = fmaf(hv.z, u1.z, A1); A1 = fmaf(hv.w, u1.w, A1);
                        A2 = fmaf(hv.x, u2.x, A2); A2 = fmaf(hv.y, u2.y, A2);
                        A2 = fmaf(hv.z, u2.z, A2); A2 = fmaf(hv.w, u2.w, A2);
                        A3 = fmaf(hv.x, u3.x, A3); A3 = fmaf(hv.y, u3.y, A3);
                        A3 = fmaf(hv.z, u3.z, A3); A3 = fmaf(hv.w, u3.w, A3);
                    }
                }
                cp0 = np0; cp1 = np1; cp2 = np2; cp3 = np3;
                if (wv == 0) pollm(flags2, lane, tl + 1);
                __syncthreads();
            }
        } else {
            // ---------------- machinery (batch = bk), 7 sync phases ----------------
            if (wv == 0) pollx(flags, lane, tl + 1);
            __syncthreads();
            // P0: activations + pre-write M norms
            if (tid < 247) {
                float v = wslot[(128 + (tid >> 2)) * 256 + b * 4 + (tid & 3)];
                float a;
                if (tid < 128) a = tanhf(v);
                else if (tid < 132) a = softplusf_(v);
                else if (tid < 164) a = tanhf(v);
                else if (tid == 164) a = softplusf_(v);
                else if (tid < 197) a = sigmoidf_(v);
                else if (tid < 229) a = tanhf(v);
                else if (tid < 235) a = sigmoidf_(v);
                else a = v;
                act[tid] = a;
            }
            if (tid < 64) {
                float s2 = 0.f;
                for (int w = 0; w < 32; ++w) {
                    float mm = M_l[tid * 33 + w];
                    s2 = fmaf(mm, mm, s2);
                }
                sM2[tid] = s2;
            }
            __syncthreads();
            // P1: wave0 serial chain (wave-synchronous)
            if (tid < 64) {
                if (tid < 4) {
                    float m0 = act[235 + 3 * tid], m1 = act[236 + 3 * tid],
                          m2 = act[237 + 3 * tid];
                    float mx = fmaxf(m0, fmaxf(m1, m2));
                    float e0 = expf(m0 - mx), e1 = expf(m1 - mx), e2 = expf(m2 - mx);
                    float s = e0 + e1 + e2;
                    modes_l[3 * tid] = e0 / s;
                    modes_l[3 * tid + 1] = e1 / s;
                    modes_l[3 * tid + 2] = e2 / s;
                    float ks = 0.f;
                    for (int w = 0; w < 32; ++w) {
                        float kk = act[tid * 32 + w];
                        ks = fmaf(kk, kk, ks);
                    }
                    kss_l[tid] = ks;
                }
                if (tid == 4) {
                    float s = 0.f;
                    for (int w = 0; w < 32; ++w) {
                        float kk = act[132 + w];
                        s = fmaf(kk, kk, s);
                    }
                    scal[0] = s;
                }
                float psi = 1.f;
#pragma unroll
                for (int r = 0; r < 4; ++r) psi *= 1.f - act[229 + r] * wr_l[r * 64 + tid];
                float un = u_l[tid], wwo = ww_l[tid];
                float unew = (un + wwo - un * wwo) * psi;
                u_l[tid] = unew;
                // stable ascending rank (wave-internal LDS)
                int rk = 0;
                for (int m = 0; m < 64; ++m) {
                    float um = u_l[m];
                    rk += (um < unew) || (um == unew && m < tid);
                }
                srt_l[rk] = unew;
                // exclusive prefix product over sorted u
                float v = srt_l[tid];
                float incl = v;
#pragma unroll
                for (int off = 1; off < 64; off <<= 1) {
                    float o = __shfl_up(incl, off);
                    if (tid >= off) incl *= o;
                }
                float excl = __shfl_up(incl, 1);
                if (tid == 0) excl = 1.f;
                asrt_l[tid] = (1.f - v) * excl;
                // content write weights
                float dot = 0.f;
                for (int w = 0; w < 32; ++w) dot = fmaf(act[132 + w], M_l[tid * 33 + w], dot);
                float logit = dot * rsqrtf(sM2[tid] + EPSF) * rsqrtf(scal[0] + EPSF) * act[164];
                float mx = logit;
#pragma unroll
                for (int off = 32; off; off >>= 1) mx = fmaxf(mx, __shfl_xor(mx, off));
                float e = expf(logit - mx);
                float s = e;
#pragma unroll
                for (int off = 32; off; off >>= 1) s += __shfl_xor(s, off);
                float cw = e / s;
                float a = asrt_l[rk];
                float agv = act[233], wgv = act[234];
                float wn = wgv * (agv * a + (1.f - agv) * cw);
                ww_l[tid] = wn;
                float sw = wn;
#pragma unroll
                for (int off = 32; off; off >>= 1) sw += __shfl_xor(sw, off);
                if (tid == 0) scal[1] = sw;
            }
            __syncthreads();
            // P2: M + L updates (4 waves)
            if (tid < 256) {
#pragma unroll
                for (int i = 0; i < 8; ++i) {
                    int e = tid + 256 * i;
                    int n = e >> 5, w = e & 31;
                    float wwn = ww_l[n];
                    M_l[n * 33 + w] =
                        M_l[n * 33 + w] * (1.f - wwn * act[165 + w]) + wwn * act[197 + w];
                }
#pragma unroll
                for (int i = 0; i < 16; ++i) {
                    int e = tid + 256 * i;
                    int n = e >> 6, m = e & 63;
                    float Lv = L_l[n * 65 + m];
                    Lv = (1.f - ww_l[n] - ww_l[m]) * Lv + ww_l[n] * p_l[m];
                    L_l[n * 65 + m] = (n == m) ? 0.f : Lv;
                }
            }
            __syncthreads();
            // P3: read weights (4 waves, r=wv) + p update (wave0)
            float wrn = 0.f;
            if (tid < 256) {
                const int r = wv;
                const int n = lane;
                if (r == 0) p_l[n] = (1.f - scal[1]) * p_l[n] + ww_l[n];
                float s2 = 0.f;
                for (int w = 0; w < 32; ++w) {
                    float mm = M_l[n * 33 + w];
                    s2 = fmaf(mm, mm, s2);
                }
                float dot = 0.f;
                for (int w = 0; w < 32; ++w) dot = fmaf(act[r * 32 + w], M_l[n * 33 + w], dot);
                float logit = dot * rsqrtf(s2 + EPSF) * rsqrtf(kss_l[r] + EPSF) * act[128 + r];
                float mx = logit;
#pragma unroll
                for (int off = 32; off; off >>= 1) mx = fmaxf(mx, __shfl_xor(mx, off));
                float e = expf(logit - mx);
                float s = e;
#pragma unroll
                for (int off = 32; off; off >>= 1) s += __shfl_xor(s, off);
                float cr = e / s;
                float fw = 0.f, bw = 0.f;
                for (int m = 0; m < 64; ++m) {
                    float wrm = wr_l[r * 64 + m];
                    fw = fmaf(L_l[n * 65 + m], wrm, fw);
                    bw = fmaf(L_l[m * 65 + n], wrm, bw);
                }
                wrn = modes_l[r * 3] * bw + modes_l[r * 3 + 1] * cr + modes_l[r * 3 + 2] * fw;
            }
            __syncthreads();
            if (tid < 256) wr_l[tid] = wrn;
            __syncthreads();
            // P4: rv + publish
            if (tid < 128) {
                const int r = tid >> 5, w = tid & 31;
                float rv = 0.f;
                for (int n = 0; n < 64; ++n) rv = fmaf(wr_l[r * 64 + n], M_l[n * 33 + w], rv);
                stg_coh(&wslot[(192 + (tid >> 2)) * 256 + b * 4 + (tid & 3)], rv);
            }
            __syncthreads();  // drains vmcnt
            if (tid == 0) st_flag(flags2 + bk * 32, tl + 1);
        }
    }
    if (valid && q == 0) CC[cell * 64 + lane] = c_reg;
    if (machb) {
        if (tid < 256) {
#pragma unroll
            for (int i = 0; i < 8; ++i) {
                int e = tid + 256 * i;
                Mg[b * 2048 + e] = M_l[(e >> 5) * 33 + (e & 31)];
            }
#pragma unroll
            for (int i = 0; i < 16; ++i) {
                int e = tid + 256 * i;
                Lg[b * 4096 + e] = L_l[(e >> 6) * 65 + (e & 63)];
            }
            WRg[b * 256 + tid] = wr_l[tid];
        }
        if (tid < 64) {
            Ug[b * 64 + tid] = u_l[tid];
            Pg[b * 64 + tid] = p_l[tid];
            WWg[b * 64 + tid] = ww_l[tid];
        }
    }
}

// ---------------------------------------------------------------------------
extern "C" void kernel_launch(void* const* d_in, const int* in_sizes, int n_in, void* d_out,
                              int out_size, void* d_ws, size_t ws_size, hipStream_t stream) {
    const float* x = (const float*)d_in[0];
    const float* Wih_e = (const float*)d_in[1];
    const float* Whh_e = (const float*)d_in[2];
    const float* b_e = (const float*)d_in[3];
    const float* Wih_c = (const float*)d_in[4];
    const float* Whh_c = (const float*)d_in[5];
    const float* b_c = (const float*)d_in[6];
    float* out = (float*)d_out;
    float* ws = (float*)d_ws;

    int TC = 32;
    while (TC > 2) {
        size_t need =
            ((size_t)11612096 + (size_t)TC * 415488 + (size_t)(512 / TC) * 16384) * 4;
        if (need <= ws_size) break;
        TC >>= 1;
    }
    const int nch = 256 / TC;
    const int M = TC * 64;

    size_t off = 0;
    float* XPT = ws + off; off += (size_t)2048 * M;
    float* CPT = ws + off; off += (size_t)3036 * M;
    float* Wcat = ws + off; off += (size_t)3036 * 896;
    float* ENC = ws + off; off += (size_t)256 * 64 * 512;
    size_t zoff = off;
    float* HSE = ws + off; off += (size_t)TC * 32768;  // enc h slots
    float* CE = ws + off; off += 512 * 64;
    float* HS = ws + off; off += (size_t)TC * 57344;   // dnc h/rv slots
    float* CC = ws + off; off += 759 * 64;
    float* Mg = ws + off; off += 64 * 2048;
    float* Ug = ws + off; off += 64 * 64;
    float* Pg = ws + off; off += 64 * 64;
    float* WWg = ws + off; off += 64 * 64;
    float* Lg = ws + off; off += 64 * 4096;
    float* WRg = ws + off; off += 64 * 256;
    int* BAR = (int*)(ws + off); off += (size_t)2 * nch * 16384;
    size_t zbytes = (off - zoff) * 4;

    hipMemsetAsync(ws + zoff, 0, zbytes, stream);
    prep_weights<<<dim3((3036 * 896 + 255) / 256), dim3(256), 0, stream>>>(Whh_c, Wih_c, Wcat);
    for (int c = 0; c < nch; ++c) {
        proj_gemm<<<dim3(32, TC), dim3(256), 0, stream>>>(x, Wih_e, b_e, XPT, 2048, 512, c * TC,
                                                          1, 256, 512, M);
        enc_seq<<<dim3(256), dim3(512), 0, stream>>>(Whh_e, XPT, HSE, CE, M, TC,
                                                     BAR + (size_t)c * 16384);
        enc_emit<<<dim3(TC, 32), dim3(256), 0, stream>>>(HSE, ENC, c * TC);
    }
    for (int c = 0; c < nch; ++c) {
        proj_gemm<<<dim3(48, TC), dim3(256), 0, stream>>>(ENC, Wih_c, b_c, CPT, 3036, 640,
                                                          c * TC * 64, 64, 1, 512, M);
        dnc_seq<<<dim3(256), dim3(1024), 0, stream>>>(Wcat, CPT, HS, CC, Mg, Ug, Pg, WWg, Lg,
                                                      WRg, M, TC, BAR + (size_t)(nch + c) * 16384);
        out_emit<<<dim3(TC, 32), dim3(256), 0, stream>>>(HS, out, c * TC);
    }
}